// Round 1
// baseline (420.424 us; speedup 1.0000x reference)
//
#include <hip/hip_runtime.h>
#include <hip/hip_bf16.h>

using bf16x8s = __attribute__((ext_vector_type(8))) short;
using f32x4   = __attribute__((ext_vector_type(4))) float;

#define DEVI __device__ __forceinline__

static constexpr int BB  = 16;    // batch
static constexpr int CC  = 512;   // channels
static constexpr int TT  = 1024;  // tokens = 32*32
static constexpr int OQ  = 1536;  // 3*C
static constexpr int NH  = 8;     // heads
static constexpr int CHD = 64;    // head dim

DEVI void load_lds16(const void* g, void* l) {
  __builtin_amdgcn_global_load_lds((const __attribute__((address_space(1))) void*)g,
                                   (__attribute__((address_space(3))) void*)l,
                                   16, 0, 0);
}

// ---------------- K0: convert weights fp32 -> bf16 ----------------
__global__ __launch_bounds__(256) void k_convert_w(const float* __restrict__ wq,
                                                   const float* __restrict__ wp,
                                                   __hip_bfloat16* __restrict__ wqb,
                                                   __hip_bfloat16* __restrict__ wpb) {
  int i = blockIdx.x * 256 + threadIdx.x;
  const int NQ = OQ * CC;                 // 786432
  if (i < NQ) wqb[i] = __float2bfloat16(wq[i]);
  else        wpb[i - NQ] = __float2bfloat16(wp[i - NQ]);   // grid covers NQ + 512*512 exactly
}

// ---------------- K1a: LayerNorm stats per (b,c) over T ----------------
__global__ __launch_bounds__(256) void k_ln_stats(const float* __restrict__ x,
                                                  float* __restrict__ mean,
                                                  float* __restrict__ rstd) {
  const int row = blockIdx.x;                    // b*C + c
  const float4* xv = (const float4*)(x + (size_t)row * TT);
  float4 v = xv[threadIdx.x];
  float s = v.x + v.y + v.z + v.w;
  float q = v.x * v.x + v.y * v.y + v.z * v.z + v.w * v.w;
  #pragma unroll
  for (int off = 1; off < 64; off <<= 1) {
    s += __shfl_xor(s, off);
    q += __shfl_xor(q, off);
  }
  __shared__ float ss[4], sq[4];
  const int wave = threadIdx.x >> 6;
  if ((threadIdx.x & 63) == 0) { ss[wave] = s; sq[wave] = q; }
  __syncthreads();
  if (threadIdx.x == 0) {
    float S = ss[0] + ss[1] + ss[2] + ss[3];
    float Q = sq[0] + sq[1] + sq[2] + sq[3];
    float m = S * (1.0f / TT);
    float var = Q * (1.0f / TT) - m * m;
    mean[row] = m;
    rstd[row] = 1.0f / sqrtf(var + 1e-5f);
  }
}

// ---------------- K1b: normalize + transpose -> xnT[b][t][c] bf16 ----------------
__global__ __launch_bounds__(256) void k_normT(const float* __restrict__ x,
                                               const float* __restrict__ mean,
                                               const float* __restrict__ rstd,
                                               __hip_bfloat16* __restrict__ xnT) {
  const int t0 = blockIdx.x * 64;
  const int c0 = blockIdx.y * 64;
  const int b  = blockIdx.z;
  __shared__ __hip_bfloat16 tile[64][66];        // stride 66 elems = 132B: conflict-free
  const int tl = threadIdx.x & 63;
  const int cb = (threadIdx.x >> 6) * 16;
  #pragma unroll
  for (int i = 0; i < 16; ++i) {
    const int cl = cb + i;
    const int gc = b * CC + c0 + cl;
    float v = x[(size_t)gc * TT + t0 + tl];
    float xn = (v - mean[gc]) * rstd[gc];
    tile[tl][cl] = __float2bfloat16(xn);
  }
  __syncthreads();
  #pragma unroll
  for (int i = 0; i < 16; ++i) {
    const int tl2 = cb + i;
    const int cl2 = tl;
    xnT[((size_t)(b * TT + t0 + tl2)) * CC + c0 + cl2] = tile[tl2][cl2];
  }
}

// ---------------- K2: QKV GEMM  (o,t) tiles, K=C ----------------
// A = w_qkv bf16 [1536][512]; B = xnT [b][t][512]; writes Q,K:[bh][t][64], V:[bh][64][t]
__global__ __launch_bounds__(256) void k_qkv_gemm(const __hip_bfloat16* __restrict__ Wq,
                                                  const __hip_bfloat16* __restrict__ Xt,
                                                  const float* __restrict__ bias,
                                                  __hip_bfloat16* __restrict__ Qb,
                                                  __hip_bfloat16* __restrict__ Kb,
                                                  __hip_bfloat16* __restrict__ Vb) {
  __shared__ __hip_bfloat16 As[128 * 64];
  __shared__ __hip_bfloat16 Bs[128 * 64];
  const int tid  = threadIdx.x;
  const int lane = tid & 63;
  const int wave = tid >> 6;
  const int wr = wave >> 1, wc = wave & 1;
  const int tn0 = blockIdx.x * 128;
  const int om0 = blockIdx.y * 128;
  const int b   = blockIdx.z;

  const __hip_bfloat16* Ab  = Wq + (size_t)om0 * CC;
  const __hip_bfloat16* Bbp = Xt + ((size_t)b * TT + tn0) * CC;

  f32x4 acc[4][4] = {};
  const int l15  = lane & 15;
  const int kgrp = (lane >> 4) << 3;

  for (int k0 = 0; k0 < CC; k0 += 64) {
    #pragma unroll
    for (int r = 0; r < 4; ++r) {
      int idx = r * 256 + tid;
      int row = idx >> 3, ch = (idx & 7) << 3;
      load_lds16(Ab + (size_t)row * CC + k0 + ch, &As[(r * 256 + wave * 64) * 8]);
    }
    #pragma unroll
    for (int r = 0; r < 4; ++r) {
      int idx = r * 256 + tid;
      int row = idx >> 3, ch = (idx & 7) << 3;
      load_lds16(Bbp + (size_t)row * CC + k0 + ch, &Bs[(r * 256 + wave * 64) * 8]);
    }
    __syncthreads();
    #pragma unroll
    for (int kk = 0; kk < 2; ++kk) {
      const int klo = kk * 32 + kgrp;
      bf16x8s af[4], bfr[4];
      #pragma unroll
      for (int mf = 0; mf < 4; ++mf)
        af[mf] = *(const bf16x8s*)&As[(wr * 64 + mf * 16 + l15) * 64 + klo];
      #pragma unroll
      for (int nf = 0; nf < 4; ++nf)
        bfr[nf] = *(const bf16x8s*)&Bs[(wc * 64 + nf * 16 + l15) * 64 + klo];
      #pragma unroll
      for (int mf = 0; mf < 4; ++mf)
        #pragma unroll
        for (int nf = 0; nf < 4; ++nf)
          acc[mf][nf] = __builtin_amdgcn_mfma_f32_16x16x32_bf16(af[mf], bfr[nf], acc[mf][nf], 0, 0, 0);
    }
    __syncthreads();
  }

  const int rg = (lane >> 4) << 2;
  #pragma unroll
  for (int mf = 0; mf < 4; ++mf) {
    #pragma unroll
    for (int j = 0; j < 4; ++j) {
      const int o  = om0 + wr * 64 + mf * 16 + rg + j;
      const int h  = o / 192;
      const int r  = o % 192;
      const int bh = b * NH + h;
      const float bv = bias[o];
      #pragma unroll
      for (int nf = 0; nf < 4; ++nf) {
        const int t = tn0 + wc * 64 + nf * 16 + l15;
        float val = acc[mf][nf][j] + bv;
        if (r < 64)       Qb[((size_t)bh * TT + t) * CHD + r]        = __float2bfloat16(val * 0.125f); // scale^2 folded into Q
        else if (r < 128) Kb[((size_t)bh * TT + t) * CHD + (r - 64)] = __float2bfloat16(val);
        else              Vb[((size_t)bh * CHD + (r - 128)) * TT + t] = __float2bfloat16(val);
      }
    }
  }
}

// ---------------- K4: flash attention. Q,K:[bh][t][64], V:[bh][64][t] -> aT[b][t][512] ----------------
__global__ __launch_bounds__(256) void k_attn(const __hip_bfloat16* __restrict__ Qb,
                                              const __hip_bfloat16* __restrict__ Kb,
                                              const __hip_bfloat16* __restrict__ Vb,
                                              __hip_bfloat16* __restrict__ aT) {
  const int qt   = blockIdx.x;      // 16 q-tiles of 64
  const int bh   = blockIdx.y;      // 128
  const int lane = threadIdx.x & 63;
  const int wave = threadIdx.x >> 6;
  const int qbase = qt * 64 + wave * 16;
  __shared__ __hip_bfloat16 Pl[4][16][64];       // per-wave P tile

  const __hip_bfloat16* Qh = Qb + (size_t)bh * TT * CHD;
  const __hip_bfloat16* Kh = Kb + (size_t)bh * TT * CHD;
  const __hip_bfloat16* Vh = Vb + (size_t)bh * CHD * TT;

  const int l15  = lane & 15;
  const int kgrp = (lane >> 4) << 3;

  bf16x8s aq[2];
  #pragma unroll
  for (int kk = 0; kk < 2; ++kk)
    aq[kk] = *(const bf16x8s*)&Qh[(size_t)(qbase + l15) * CHD + kk * 32 + kgrp];

  float m_run[4], l_run[4];
  f32x4 oacc[4] = {};
  #pragma unroll
  for (int j = 0; j < 4; ++j) { m_run[j] = -1e30f; l_run[j] = 0.f; }

  for (int st = 0; st < 16; ++st) {
    const int s0 = st * 64;
    f32x4 sfr[4] = {};
    #pragma unroll
    for (int kk = 0; kk < 2; ++kk) {
      const int klo = kk * 32 + kgrp;
      #pragma unroll
      for (int nf = 0; nf < 4; ++nf) {
        bf16x8s bk = *(const bf16x8s*)&Kh[(size_t)(s0 + nf * 16 + l15) * CHD + klo];
        sfr[nf] = __builtin_amdgcn_mfma_f32_16x16x32_bf16(aq[kk], bk, sfr[nf], 0, 0, 0);
      }
    }
    // online softmax; row r = (lane>>4)*4 + j lives across the 16 lanes of the group
    float p[4][4];
    #pragma unroll
    for (int j = 0; j < 4; ++j) {
      float v = fmaxf(fmaxf(sfr[0][j], sfr[1][j]), fmaxf(sfr[2][j], sfr[3][j]));
      #pragma unroll
      for (int off = 1; off < 16; off <<= 1) v = fmaxf(v, __shfl_xor(v, off));
      const float mn = fmaxf(m_run[j], v);
      const float alpha = __expf(m_run[j] - mn);
      float rs = 0.f;
      #pragma unroll
      for (int nf = 0; nf < 4; ++nf) { float pv = __expf(sfr[nf][j] - mn); p[nf][j] = pv; rs += pv; }
      #pragma unroll
      for (int off = 1; off < 16; off <<= 1) rs += __shfl_xor(rs, off);
      l_run[j] = l_run[j] * alpha + rs;
      m_run[j] = mn;
      #pragma unroll
      for (int cf = 0; cf < 4; ++cf) oacc[cf][j] *= alpha;
    }
    // P -> LDS (per-wave buffer; in-order DS within a wave, no barrier needed)
    const int prow = (lane >> 4) << 2;
    #pragma unroll
    for (int nf = 0; nf < 4; ++nf)
      #pragma unroll
      for (int j = 0; j < 4; ++j)
        Pl[wave][prow + j][nf * 16 + l15] = __float2bfloat16(p[nf][j]);
    // PV
    #pragma unroll
    for (int kk = 0; kk < 2; ++kk) {
      const int klo = kk * 32 + kgrp;
      bf16x8s pa = *(const bf16x8s*)&Pl[wave][l15][klo];
      #pragma unroll
      for (int cf = 0; cf < 4; ++cf) {
        bf16x8s bv = *(const bf16x8s*)&Vh[(size_t)(cf * 16 + l15) * TT + s0 + klo];
        oacc[cf] = __builtin_amdgcn_mfma_f32_16x16x32_bf16(pa, bv, oacc[cf], 0, 0, 0);
      }
    }
  }
  // epilogue: aT[b][t][h*64+c] = O / l
  const int b = bh >> 3, h = bh & 7;
  const int rg = (lane >> 4) << 2;
  #pragma unroll
  for (int cf = 0; cf < 4; ++cf)
    #pragma unroll
    for (int j = 0; j < 4; ++j) {
      const int t = qbase + rg + j;
      const int c = h * CHD + cf * 16 + l15;
      aT[((size_t)b * TT + t) * CC + c] = __float2bfloat16(oacc[cf][j] / l_run[j]);
    }
}

// ---------------- K5: proj GEMM + bias + xn residual ----------------
__global__ __launch_bounds__(256) void k_proj_gemm(const __hip_bfloat16* __restrict__ Wp,
                                                   const __hip_bfloat16* __restrict__ At,
                                                   const float* __restrict__ bias,
                                                   const float* __restrict__ x,
                                                   const float* __restrict__ mean,
                                                   const float* __restrict__ rstd,
                                                   float* __restrict__ out) {
  __shared__ __hip_bfloat16 As[128 * 64];
  __shared__ __hip_bfloat16 Bs[128 * 64];
  const int tid  = threadIdx.x;
  const int lane = tid & 63;
  const int wave = tid >> 6;
  const int wr = wave >> 1, wc = wave & 1;
  const int tn0 = blockIdx.x * 128;
  const int om0 = blockIdx.y * 128;
  const int b   = blockIdx.z;

  const __hip_bfloat16* Ab  = Wp + (size_t)om0 * CC;
  const __hip_bfloat16* Bbp = At + ((size_t)b * TT + tn0) * CC;

  f32x4 acc[4][4] = {};
  const int l15  = lane & 15;
  const int kgrp = (lane >> 4) << 3;

  for (int k0 = 0; k0 < CC; k0 += 64) {
    #pragma unroll
    for (int r = 0; r < 4; ++r) {
      int idx = r * 256 + tid;
      int row = idx >> 3, ch = (idx & 7) << 3;
      load_lds16(Ab + (size_t)row * CC + k0 + ch, &As[(r * 256 + wave * 64) * 8]);
    }
    #pragma unroll
    for (int r = 0; r < 4; ++r) {
      int idx = r * 256 + tid;
      int row = idx >> 3, ch = (idx & 7) << 3;
      load_lds16(Bbp + (size_t)row * CC + k0 + ch, &Bs[(r * 256 + wave * 64) * 8]);
    }
    __syncthreads();
    #pragma unroll
    for (int kk = 0; kk < 2; ++kk) {
      const int klo = kk * 32 + kgrp;
      bf16x8s af[4], bfr[4];
      #pragma unroll
      for (int mf = 0; mf < 4; ++mf)
        af[mf] = *(const bf16x8s*)&As[(wr * 64 + mf * 16 + l15) * 64 + klo];
      #pragma unroll
      for (int nf = 0; nf < 4; ++nf)
        bfr[nf] = *(const bf16x8s*)&Bs[(wc * 64 + nf * 16 + l15) * 64 + klo];
      #pragma unroll
      for (int mf = 0; mf < 4; ++mf)
        #pragma unroll
        for (int nf = 0; nf < 4; ++nf)
          acc[mf][nf] = __builtin_amdgcn_mfma_f32_16x16x32_bf16(af[mf], bfr[nf], acc[mf][nf], 0, 0, 0);
    }
    __syncthreads();
  }

  const int rg = (lane >> 4) << 2;
  #pragma unroll
  for (int mf = 0; mf < 4; ++mf) {
    #pragma unroll
    for (int j = 0; j < 4; ++j) {
      const int o = om0 + wr * 64 + mf * 16 + rg + j;
      const int gco = b * CC + o;
      const float bv = bias[o];
      const float mu = mean[gco], rs = rstd[gco];
      #pragma unroll
      for (int nf = 0; nf < 4; ++nf) {
        const int t = tn0 + wc * 64 + nf * 16 + l15;
        const size_t xi = (size_t)gco * TT + t;
        float xn = (x[xi] - mu) * rs;
        out[xi] = xn + acc[mf][nf][j] + bv;
      }
    }
  }
}

extern "C" void kernel_launch(void* const* d_in, const int* in_sizes, int n_in,
                              void* d_out, int out_size, void* d_ws, size_t ws_size,
                              hipStream_t stream) {
  const float* x  = (const float*)d_in[0];
  const float* wq = (const float*)d_in[1];
  const float* bq = (const float*)d_in[2];
  const float* wp = (const float*)d_in[3];
  const float* bp = (const float*)d_in[4];
  float* out = (float*)d_out;

  char* ws = (char*)d_ws;
  __hip_bfloat16* wqb = (__hip_bfloat16*)(ws);                  // 1536*512*2      = 1,572,864
  __hip_bfloat16* wpb = (__hip_bfloat16*)(ws + 1572864);        // 512*512*2       =   524,288
  float*          mean = (float*)(ws + 2097152);                // 8192*4
  float*          rstd = (float*)(ws + 2129920);                // 8192*4
  __hip_bfloat16* xnT = (__hip_bfloat16*)(ws + 2162688);        // 16*1024*512*2   = 16,777,216
  __hip_bfloat16* Qb  = (__hip_bfloat16*)(ws + 18939904);       // 128*1024*64*2
  __hip_bfloat16* Kb  = (__hip_bfloat16*)(ws + 35717120);
  __hip_bfloat16* Vb  = (__hip_bfloat16*)(ws + 52494336);       // ends 69,271,552
  __hip_bfloat16* aT  = xnT;   // alias: xnT fully consumed by k_qkv_gemm before k_attn writes aT

  k_convert_w<<<4096, 256, 0, stream>>>(wq, wp, wqb, wpb);
  k_ln_stats<<<BB * CC, 256, 0, stream>>>(x, mean, rstd);
  k_normT<<<dim3(TT / 64, CC / 64, BB), 256, 0, stream>>>(x, mean, rstd, xnT);
  k_qkv_gemm<<<dim3(TT / 128, OQ / 128, BB), 256, 0, stream>>>(wqb, xnT, bq, Qb, Kb, Vb);
  k_attn<<<dim3(TT / 64, BB * NH), 256, 0, stream>>>(Qb, Kb, Vb, aT);
  k_proj_gemm<<<dim3(TT / 128, CC / 128, BB), 256, 0, stream>>>(wpb, aT, bp, x, mean, rstd, out);
}

// Round 2
// 344.248 us; speedup vs baseline: 1.2213x; 1.2213x over previous
//
#include <hip/hip_runtime.h>
#include <hip/hip_bf16.h>

using bf16x8s = __attribute__((ext_vector_type(8))) short;
using f32x4   = __attribute__((ext_vector_type(4))) float;
using f32x16  = __attribute__((ext_vector_type(16))) float;
using u32x4   = __attribute__((ext_vector_type(4))) unsigned int;

#define DEVI __device__ __forceinline__

static constexpr int BB  = 16;    // batch
static constexpr int CC  = 512;   // channels
static constexpr int TT  = 1024;  // tokens = 32*32
static constexpr int OQ  = 1536;  // 3*C
static constexpr int NH  = 8;     // heads
static constexpr int CHD = 64;    // head dim

DEVI void load_lds16(const void* g, void* l) {
  __builtin_amdgcn_global_load_lds((const __attribute__((address_space(1))) void*)g,
                                   (__attribute__((address_space(3))) void*)l,
                                   16, 0, 0);
}

DEVI unsigned int cvtpk_bf16(float lo, float hi) {
  unsigned int r;
  asm("v_cvt_pk_bf16_f32 %0, %1, %2" : "=v"(r) : "v"(lo), "v"(hi));
  return r;
}

// permlane32_swap(a,b): x = (lane>=32 ? b-of-partner : own a); y = (lane>=32 ? own b : a-of-partner)
DEVI void plswap(unsigned int a, unsigned int b, unsigned int& x, unsigned int& y) {
#if __has_builtin(__builtin_amdgcn_permlane32_swap)
  auto r = __builtin_amdgcn_permlane32_swap((int)a, (int)b, false, false);
  x = (unsigned int)r[0];
  y = (unsigned int)r[1];
#else
  unsigned int pa = (unsigned int)__shfl_xor((int)a, 32);
  unsigned int pb = (unsigned int)__shfl_xor((int)b, 32);
  const bool hi = (threadIdx.x & 32) != 0;
  x = hi ? pb : a;
  y = hi ? b : pa;
#endif
}

// ---------------- K0: convert weights fp32 -> bf16 ----------------
__global__ __launch_bounds__(256) void k_convert_w(const float* __restrict__ wq,
                                                   const float* __restrict__ wp,
                                                   __hip_bfloat16* __restrict__ wqb,
                                                   __hip_bfloat16* __restrict__ wpb) {
  int i = blockIdx.x * 256 + threadIdx.x;
  const int NQ = OQ * CC;                 // 786432
  if (i < NQ) wqb[i] = __float2bfloat16(wq[i]);
  else        wpb[i - NQ] = __float2bfloat16(wp[i - NQ]);   // grid covers NQ + 512*512 exactly
}

// ---------------- K1a: LayerNorm stats per (b,c) over T ----------------
__global__ __launch_bounds__(256) void k_ln_stats(const float* __restrict__ x,
                                                  float* __restrict__ mean,
                                                  float* __restrict__ rstd) {
  const int row = blockIdx.x;                    // b*C + c
  const float4* xv = (const float4*)(x + (size_t)row * TT);
  float4 v = xv[threadIdx.x];
  float s = v.x + v.y + v.z + v.w;
  float q = v.x * v.x + v.y * v.y + v.z * v.z + v.w * v.w;
  #pragma unroll
  for (int off = 1; off < 64; off <<= 1) {
    s += __shfl_xor(s, off);
    q += __shfl_xor(q, off);
  }
  __shared__ float ss[4], sq[4];
  const int wave = threadIdx.x >> 6;
  if ((threadIdx.x & 63) == 0) { ss[wave] = s; sq[wave] = q; }
  __syncthreads();
  if (threadIdx.x == 0) {
    float S = ss[0] + ss[1] + ss[2] + ss[3];
    float Q = sq[0] + sq[1] + sq[2] + sq[3];
    float m = S * (1.0f / TT);
    float var = Q * (1.0f / TT) - m * m;
    mean[row] = m;
    rstd[row] = 1.0f / sqrtf(var + 1e-5f);
  }
}

// ---------------- K1b: normalize + transpose -> xnT[b][t][c] bf16 ----------------
__global__ __launch_bounds__(256) void k_normT(const float* __restrict__ x,
                                               const float* __restrict__ mean,
                                               const float* __restrict__ rstd,
                                               __hip_bfloat16* __restrict__ xnT) {
  const int t0 = blockIdx.x * 64;
  const int c0 = blockIdx.y * 64;
  const int b  = blockIdx.z;
  __shared__ __hip_bfloat16 tile[64][66];        // stride 66 elems = 132B: conflict-free
  const int tl = threadIdx.x & 63;
  const int cb = (threadIdx.x >> 6) * 16;
  #pragma unroll
  for (int i = 0; i < 16; ++i) {
    const int cl = cb + i;
    const int gc = b * CC + c0 + cl;
    float v = x[(size_t)gc * TT + t0 + tl];
    float xn = (v - mean[gc]) * rstd[gc];
    tile[tl][cl] = __float2bfloat16(xn);
  }
  __syncthreads();
  #pragma unroll
  for (int i = 0; i < 16; ++i) {
    const int tl2 = cb + i;
    const int cl2 = tl;
    xnT[((size_t)(b * TT + t0 + tl2)) * CC + c0 + cl2] = tile[tl2][cl2];
  }
}

// ---------------- K2: QKV GEMM  (o,t) tiles, K=C ----------------
// A = w_qkv bf16 [1536][512]; B = xnT [b][t][512]; writes Q,K:[bh][t][64], V:[bh][64][t]
__global__ __launch_bounds__(256) void k_qkv_gemm(const __hip_bfloat16* __restrict__ Wq,
                                                  const __hip_bfloat16* __restrict__ Xt,
                                                  const float* __restrict__ bias,
                                                  __hip_bfloat16* __restrict__ Qb,
                                                  __hip_bfloat16* __restrict__ Kb,
                                                  __hip_bfloat16* __restrict__ Vb) {
  __shared__ __hip_bfloat16 As[128 * 64];
  __shared__ __hip_bfloat16 Bs[128 * 64];
  const int tid  = threadIdx.x;
  const int lane = tid & 63;
  const int wave = tid >> 6;
  const int wr = wave >> 1, wc = wave & 1;
  const int tn0 = blockIdx.x * 128;
  const int om0 = blockIdx.y * 128;
  const int b   = blockIdx.z;

  const __hip_bfloat16* Ab  = Wq + (size_t)om0 * CC;
  const __hip_bfloat16* Bbp = Xt + ((size_t)b * TT + tn0) * CC;

  f32x4 acc[4][4] = {};
  const int l15  = lane & 15;
  const int kgrp = (lane >> 4) << 3;

  for (int k0 = 0; k0 < CC; k0 += 64) {
    #pragma unroll
    for (int r = 0; r < 4; ++r) {
      int idx = r * 256 + tid;
      int row = idx >> 3, ch = (idx & 7) << 3;
      load_lds16(Ab + (size_t)row * CC + k0 + ch, &As[(r * 256 + wave * 64) * 8]);
    }
    #pragma unroll
    for (int r = 0; r < 4; ++r) {
      int idx = r * 256 + tid;
      int row = idx >> 3, ch = (idx & 7) << 3;
      load_lds16(Bbp + (size_t)row * CC + k0 + ch, &Bs[(r * 256 + wave * 64) * 8]);
    }
    __syncthreads();
    #pragma unroll
    for (int kk = 0; kk < 2; ++kk) {
      const int klo = kk * 32 + kgrp;
      bf16x8s af[4], bfr[4];
      #pragma unroll
      for (int mf = 0; mf < 4; ++mf)
        af[mf] = *(const bf16x8s*)&As[(wr * 64 + mf * 16 + l15) * 64 + klo];
      #pragma unroll
      for (int nf = 0; nf < 4; ++nf)
        bfr[nf] = *(const bf16x8s*)&Bs[(wc * 64 + nf * 16 + l15) * 64 + klo];
      #pragma unroll
      for (int mf = 0; mf < 4; ++mf)
        #pragma unroll
        for (int nf = 0; nf < 4; ++nf)
          acc[mf][nf] = __builtin_amdgcn_mfma_f32_16x16x32_bf16(af[mf], bfr[nf], acc[mf][nf], 0, 0, 0);
    }
    __syncthreads();
  }

  const int rg = (lane >> 4) << 2;
  #pragma unroll
  for (int mf = 0; mf < 4; ++mf) {
    #pragma unroll
    for (int j = 0; j < 4; ++j) {
      const int o  = om0 + wr * 64 + mf * 16 + rg + j;
      const int h  = o / 192;
      const int r  = o % 192;
      const int bh = b * NH + h;
      const float bv = bias[o];
      #pragma unroll
      for (int nf = 0; nf < 4; ++nf) {
        const int t = tn0 + wc * 64 + nf * 16 + l15;
        float val = acc[mf][nf][j] + bv;
        if (r < 64)       Qb[((size_t)bh * TT + t) * CHD + r]        = __float2bfloat16(val * 0.125f); // scale^2 folded into Q
        else if (r < 128) Kb[((size_t)bh * TT + t) * CHD + (r - 64)] = __float2bfloat16(val);
        else              Vb[((size_t)bh * CHD + (r - 128)) * TT + t] = __float2bfloat16(val);
      }
    }
  }
}

// ---------------- K4: flash attention, swapped-operand 32x32 structure ----------------
// Q,K:[bh][t][64], V:[bh][64][t] -> aT[b][t][512]
// QK^T swapped: D[s][q] = mfma(A=K(32s x 16d), B=Q^T(16d x 32q)); col=q=lane&31,
// row s = (r&3)+8*(r>>2)+4*(lane>>5). Each lane owns the full P-row of ONE q.
// PV swapped:  D[d][q] = mfma(A=V^T(32d x 16s), B=P^T(16s x 32q)); O column stays q,
// so m/l/rescale/divide are lane-local scalars.
// P^T B-frag for k-step ks needs P[q][16ks+8*hi+j]; lane(q,hi) owns s=(c)+8g+4hi (g=0..7,c=0..3).
// With wA_g=cvtpk(p[8g+4hi+0],p[8g+4hi+1]), wB_g=cvtpk(+2,+3):
//   r1=plswap(wA_{2ks},wA_{2ks+1}), r2=plswap(wB_{2ks},wB_{2ks+1})
//   frag words = [r1.x, r2.x, r1.y, r2.y]  (verified for both hi halves).
__global__ __launch_bounds__(256) void k_attn(const __hip_bfloat16* __restrict__ Qb,
                                              const __hip_bfloat16* __restrict__ Kb,
                                              const __hip_bfloat16* __restrict__ Vb,
                                              __hip_bfloat16* __restrict__ aT) {
  const int lane = threadIdx.x & 63;
  const int wave = threadIdx.x >> 6;
  const int bh   = blockIdx.y;
  const int q0   = blockIdx.x * 128 + wave * 32;   // 32 q-rows per wave
  const int l31  = lane & 31;
  const int hi8  = (lane >> 5) << 3;

  const __hip_bfloat16* Qh = Qb + (size_t)bh * TT * CHD;
  const __hip_bfloat16* Kh = Kb + (size_t)bh * TT * CHD;
  const __hip_bfloat16* Vh = Vb + (size_t)bh * CHD * TT;

  // Q B-frags: lane holds Q[q0+l31][16*dstep + hi8 + j]
  bf16x8s aq[4];
  #pragma unroll
  for (int d = 0; d < 4; ++d)
    aq[d] = *(const bf16x8s*)&Qh[(size_t)(q0 + l31) * CHD + d * 16 + hi8];

  f32x16 oacc0 = {}, oacc1 = {};
  float m_run = -1e30f, l_run = 0.f;

  for (int kv0 = 0; kv0 < TT; kv0 += 64) {
    // ---- issue K and V loads up front (V consumed after softmax) ----
    bf16x8s kf0[4], kf1[4], vf0[4], vf1[4];
    #pragma unroll
    for (int d = 0; d < 4; ++d) {
      kf0[d] = *(const bf16x8s*)&Kh[(size_t)(kv0 + l31) * CHD + d * 16 + hi8];
      kf1[d] = *(const bf16x8s*)&Kh[(size_t)(kv0 + 32 + l31) * CHD + d * 16 + hi8];
    }
    #pragma unroll
    for (int ks = 0; ks < 4; ++ks) {
      vf0[ks] = *(const bf16x8s*)&Vh[(size_t)(l31) * TT + kv0 + ks * 16 + hi8];
      vf1[ks] = *(const bf16x8s*)&Vh[(size_t)(32 + l31) * TT + kv0 + ks * 16 + hi8];
    }

    // ---- QK^T: two 32x32 S-tiles ----
    f32x16 s0 = {}, s1 = {};
    #pragma unroll
    for (int d = 0; d < 4; ++d) {
      s0 = __builtin_amdgcn_mfma_f32_32x32x16_bf16(kf0[d], aq[d], s0, 0, 0, 0);
      s1 = __builtin_amdgcn_mfma_f32_32x32x16_bf16(kf1[d], aq[d], s1, 0, 0, 0);
    }

    // ---- row max (tree over 32 local values + one cross-half exchange) ----
    float t16[16];
    #pragma unroll
    for (int i = 0; i < 16; ++i) t16[i] = fmaxf(s0[i], s1[i]);
    float t8[8];
    #pragma unroll
    for (int i = 0; i < 8; ++i) t8[i] = fmaxf(t16[i], t16[i + 8]);
    float t4[4];
    #pragma unroll
    for (int i = 0; i < 4; ++i) t4[i] = fmaxf(t8[i], t8[i + 4]);
    float lmax = fmaxf(fmaxf(t4[0], t4[1]), fmaxf(t4[2], t4[3]));
    float pmax = fmaxf(lmax, __shfl_xor(lmax, 32));

    // ---- defer-max (T13, THR=8): skip rescale when growth small ----
    if (!__all(pmax <= m_run + 8.0f)) {
      const float mnew  = fmaxf(m_run, pmax);
      const float alpha = __expf(m_run - mnew);
      m_run = mnew;
      l_run *= alpha;
      #pragma unroll
      for (int i = 0; i < 16; ++i) { oacc0[i] *= alpha; oacc1[i] *= alpha; }
    }

    // ---- p = exp(s - m), in place; row sum ----
    #pragma unroll
    for (int i = 0; i < 16; ++i) s0[i] = __expf(s0[i] - m_run);
    #pragma unroll
    for (int i = 0; i < 16; ++i) s1[i] = __expf(s1[i] - m_run);
    float a8[8];
    #pragma unroll
    for (int i = 0; i < 8; ++i) a8[i] = (s0[i] + s0[i + 8]) + (s1[i] + s1[i + 8]);
    float a4[4];
    #pragma unroll
    for (int i = 0; i < 4; ++i) a4[i] = a8[i] + a8[i + 4];
    float lsum = (a4[0] + a4[1]) + (a4[2] + a4[3]);
    lsum += __shfl_xor(lsum, 32);
    l_run += lsum;

    // ---- pack P to bf16 words: wA_g, wB_g for g=0..7 (g>>2 = tile, r=4*(g&3)+c) ----
    unsigned int wa[8], wb[8];
    #pragma unroll
    for (int g = 0; g < 4; ++g) {
      wa[g]     = cvtpk_bf16(s0[4 * g + 0], s0[4 * g + 1]);
      wb[g]     = cvtpk_bf16(s0[4 * g + 2], s0[4 * g + 3]);
      wa[g + 4] = cvtpk_bf16(s1[4 * g + 0], s1[4 * g + 1]);
      wb[g + 4] = cvtpk_bf16(s1[4 * g + 2], s1[4 * g + 3]);
    }

    // ---- PV: 4 k-steps x 2 d-blocks ----
    #pragma unroll
    for (int ks = 0; ks < 4; ++ks) {
      unsigned int x0, y0, x1, y1;
      plswap(wa[2 * ks], wa[2 * ks + 1], x0, y0);
      plswap(wb[2 * ks], wb[2 * ks + 1], x1, y1);
      bf16x8s pf = __builtin_bit_cast(bf16x8s, (u32x4){x0, x1, y0, y1});
      oacc0 = __builtin_amdgcn_mfma_f32_32x32x16_bf16(vf0[ks], pf, oacc0, 0, 0, 0);
      oacc1 = __builtin_amdgcn_mfma_f32_32x32x16_bf16(vf1[ks], pf, oacc1, 0, 0, 0);
    }
  }

  // ---- epilogue: O[d][q] / l -> aT[b][t=q][h*64+d]; lane writes 8B chunks ----
  const int b = bh >> 3, h = bh & 7;
  const float rl = 1.0f / l_run;
  const int t = q0 + l31;
  __hip_bfloat16* arow = aT + ((size_t)(b * TT + t)) * CC + h * CHD;
  const int hi4 = hi8 >> 1;
  #pragma unroll
  for (int rr = 0; rr < 4; ++rr) {
    {
      const int c0 = rr * 8 + hi4;
      unsigned int lo = cvtpk_bf16(oacc0[4 * rr + 0] * rl, oacc0[4 * rr + 1] * rl);
      unsigned int hw = cvtpk_bf16(oacc0[4 * rr + 2] * rl, oacc0[4 * rr + 3] * rl);
      *(uint2*)&arow[c0] = make_uint2(lo, hw);
    }
    {
      const int c0 = 32 + rr * 8 + hi4;
      unsigned int lo = cvtpk_bf16(oacc1[4 * rr + 0] * rl, oacc1[4 * rr + 1] * rl);
      unsigned int hw = cvtpk_bf16(oacc1[4 * rr + 2] * rl, oacc1[4 * rr + 3] * rl);
      *(uint2*)&arow[c0] = make_uint2(lo, hw);
    }
  }
}

// ---------------- K5: proj GEMM + bias + xn residual ----------------
__global__ __launch_bounds__(256) void k_proj_gemm(const __hip_bfloat16* __restrict__ Wp,
                                                   const __hip_bfloat16* __restrict__ At,
                                                   const float* __restrict__ bias,
                                                   const float* __restrict__ x,
                                                   const float* __restrict__ mean,
                                                   const float* __restrict__ rstd,
                                                   float* __restrict__ out) {
  __shared__ __hip_bfloat16 As[128 * 64];
  __shared__ __hip_bfloat16 Bs[128 * 64];
  const int tid  = threadIdx.x;
  const int lane = tid & 63;
  const int wave = tid >> 6;
  const int wr = wave >> 1, wc = wave & 1;
  const int tn0 = blockIdx.x * 128;
  const int om0 = blockIdx.y * 128;
  const int b   = blockIdx.z;

  const __hip_bfloat16* Ab  = Wp + (size_t)om0 * CC;
  const __hip_bfloat16* Bbp = At + ((size_t)b * TT + tn0) * CC;

  f32x4 acc[4][4] = {};
  const int l15  = lane & 15;
  const int kgrp = (lane >> 4) << 3;

  for (int k0 = 0; k0 < CC; k0 += 64) {
    #pragma unroll
    for (int r = 0; r < 4; ++r) {
      int idx = r * 256 + tid;
      int row = idx >> 3, ch = (idx & 7) << 3;
      load_lds16(Ab + (size_t)row * CC + k0 + ch, &As[(r * 256 + wave * 64) * 8]);
    }
    #pragma unroll
    for (int r = 0; r < 4; ++r) {
      int idx = r * 256 + tid;
      int row = idx >> 3, ch = (idx & 7) << 3;
      load_lds16(Bbp + (size_t)row * CC + k0 + ch, &Bs[(r * 256 + wave * 64) * 8]);
    }
    __syncthreads();
    #pragma unroll
    for (int kk = 0; kk < 2; ++kk) {
      const int klo = kk * 32 + kgrp;
      bf16x8s af[4], bfr[4];
      #pragma unroll
      for (int mf = 0; mf < 4; ++mf)
        af[mf] = *(const bf16x8s*)&As[(wr * 64 + mf * 16 + l15) * 64 + klo];
      #pragma unroll
      for (int nf = 0; nf < 4; ++nf)
        bfr[nf] = *(const bf16x8s*)&Bs[(wc * 64 + nf * 16 + l15) * 64 + klo];
      #pragma unroll
      for (int mf = 0; mf < 4; ++mf)
        #pragma unroll
        for (int nf = 0; nf < 4; ++nf)
          acc[mf][nf] = __builtin_amdgcn_mfma_f32_16x16x32_bf16(af[mf], bfr[nf], acc[mf][nf], 0, 0, 0);
    }
    __syncthreads();
  }

  const int rg = (lane >> 4) << 2;
  #pragma unroll
  for (int mf = 0; mf < 4; ++mf) {
    #pragma unroll
    for (int j = 0; j < 4; ++j) {
      const int o = om0 + wr * 64 + mf * 16 + rg + j;
      const int gco = b * CC + o;
      const float bv = bias[o];
      const float mu = mean[gco], rs = rstd[gco];
      #pragma unroll
      for (int nf = 0; nf < 4; ++nf) {
        const int t = tn0 + wc * 64 + nf * 16 + l15;
        const size_t xi = (size_t)gco * TT + t;
        float xn = (x[xi] - mu) * rs;
        out[xi] = xn + acc[mf][nf][j] + bv;
      }
    }
  }
}

extern "C" void kernel_launch(void* const* d_in, const int* in_sizes, int n_in,
                              void* d_out, int out_size, void* d_ws, size_t ws_size,
                              hipStream_t stream) {
  const float* x  = (const float*)d_in[0];
  const float* wq = (const float*)d_in[1];
  const float* bq = (const float*)d_in[2];
  const float* wp = (const float*)d_in[3];
  const float* bp = (const float*)d_in[4];
  float* out = (float*)d_out;

  char* ws = (char*)d_ws;
  __hip_bfloat16* wqb = (__hip_bfloat16*)(ws);                  // 1536*512*2      = 1,572,864
  __hip_bfloat16* wpb = (__hip_bfloat16*)(ws + 1572864);        // 512*512*2       =   524,288
  float*          mean = (float*)(ws + 2097152);                // 8192*4
  float*          rstd = (float*)(ws + 2129920);                // 8192*4
  __hip_bfloat16* xnT = (__hip_bfloat16*)(ws + 2162688);        // 16*1024*512*2   = 16,777,216
  __hip_bfloat16* Qb  = (__hip_bfloat16*)(ws + 18939904);       // 128*1024*64*2
  __hip_bfloat16* Kb  = (__hip_bfloat16*)(ws + 35717120);
  __hip_bfloat16* Vb  = (__hip_bfloat16*)(ws + 52494336);       // ends 69,271,552
  __hip_bfloat16* aT  = xnT;   // alias: xnT fully consumed by k_qkv_gemm before k_attn writes aT

  k_convert_w<<<4096, 256, 0, stream>>>(wq, wp, wqb, wpb);
  k_ln_stats<<<BB * CC, 256, 0, stream>>>(x, mean, rstd);
  k_normT<<<dim3(TT / 64, CC / 64, BB), 256, 0, stream>>>(x, mean, rstd, xnT);
  k_qkv_gemm<<<dim3(TT / 128, OQ / 128, BB), 256, 0, stream>>>(wqb, xnT, bq, Qb, Kb, Vb);
  k_attn<<<dim3(TT / 128, BB * NH), 256, 0, stream>>>(Qb, Kb, Vb, aT);
  k_proj_gemm<<<dim3(TT / 128, CC / 128, BB), 256, 0, stream>>>(wpb, aT, bp, x, mean, rstd, out);
}

// Round 4
// 250.148 us; speedup vs baseline: 1.6807x; 1.3762x over previous
//
#include <hip/hip_runtime.h>
#include <hip/hip_bf16.h>

using bf16x8s = __attribute__((ext_vector_type(8))) short;
using f32x4   = __attribute__((ext_vector_type(4))) float;
using f32x16  = __attribute__((ext_vector_type(16))) float;
using u32x4   = __attribute__((ext_vector_type(4))) unsigned int;

#define DEVI __device__ __forceinline__

static constexpr int BB  = 16;    // batch
static constexpr int CC  = 512;   // channels
static constexpr int TT  = 1024;  // tokens = 32*32
static constexpr int OQ  = 1536;  // 3*C
static constexpr int NH  = 8;     // heads
static constexpr int CHD = 64;    // head dim

DEVI void load_lds16(const void* g, void* l) {
  __builtin_amdgcn_global_load_lds((const __attribute__((address_space(1))) void*)g,
                                   (__attribute__((address_space(3))) void*)l,
                                   16, 0, 0);
}

DEVI unsigned int cvtpk_bf16(float lo, float hi) {
  unsigned int r;
  asm("v_cvt_pk_bf16_f32 %0, %1, %2" : "=v"(r) : "v"(lo), "v"(hi));
  return r;
}

// permlane32_swap(a,b): x = (lane>=32 ? b-of-partner : own a); y = (lane>=32 ? own b : a-of-partner)
DEVI void plswap(unsigned int a, unsigned int b, unsigned int& x, unsigned int& y) {
#if __has_builtin(__builtin_amdgcn_permlane32_swap)
  auto r = __builtin_amdgcn_permlane32_swap((int)a, (int)b, false, false);
  x = (unsigned int)r[0];
  y = (unsigned int)r[1];
#else
  unsigned int pa = (unsigned int)__shfl_xor((int)a, 32);
  unsigned int pb = (unsigned int)__shfl_xor((int)b, 32);
  const bool hi = (threadIdx.x & 32) != 0;
  x = hi ? pb : a;
  y = hi ? b : pa;
#endif
}

// ---------------- K0: convert weights fp32 -> bf16 ----------------
__global__ __launch_bounds__(256) void k_convert_w(const float* __restrict__ wq,
                                                   const float* __restrict__ wp,
                                                   __hip_bfloat16* __restrict__ wqb,
                                                   __hip_bfloat16* __restrict__ wpb) {
  int i = blockIdx.x * 256 + threadIdx.x;
  const int NQ = OQ * CC;                 // 786432
  if (i < NQ) wqb[i] = __float2bfloat16(wq[i]);
  else        wpb[i - NQ] = __float2bfloat16(wp[i - NQ]);   // grid covers NQ + 512*512 exactly
}

// ---------------- K1a: LayerNorm stats per (b,c) over T ----------------
__global__ __launch_bounds__(256) void k_ln_stats(const float* __restrict__ x,
                                                  float* __restrict__ mean,
                                                  float* __restrict__ rstd) {
  const int row = blockIdx.x;                    // b*C + c
  const float4* xv = (const float4*)(x + (size_t)row * TT);
  float4 v = xv[threadIdx.x];
  float s = v.x + v.y + v.z + v.w;
  float q = v.x * v.x + v.y * v.y + v.z * v.z + v.w * v.w;
  #pragma unroll
  for (int off = 1; off < 64; off <<= 1) {
    s += __shfl_xor(s, off);
    q += __shfl_xor(q, off);
  }
  __shared__ float ss[4], sq[4];
  const int wave = threadIdx.x >> 6;
  if ((threadIdx.x & 63) == 0) { ss[wave] = s; sq[wave] = q; }
  __syncthreads();
  if (threadIdx.x == 0) {
    float S = ss[0] + ss[1] + ss[2] + ss[3];
    float Q = sq[0] + sq[1] + sq[2] + sq[3];
    float m = S * (1.0f / TT);
    float var = Q * (1.0f / TT) - m * m;
    mean[row] = m;
    rstd[row] = 1.0f / sqrtf(var + 1e-5f);
  }
}

// ---------------- K1b: normalize + transpose -> xnT[b][t][c] bf16 ----------------
__global__ __launch_bounds__(256) void k_normT(const float* __restrict__ x,
                                               const float* __restrict__ mean,
                                               const float* __restrict__ rstd,
                                               __hip_bfloat16* __restrict__ xnT) {
  const int t0 = blockIdx.x * 64;
  const int c0 = blockIdx.y * 64;
  const int b  = blockIdx.z;
  __shared__ __hip_bfloat16 tile[64][66];        // stride 66 elems = 132B: conflict-free
  const int tl = threadIdx.x & 63;
  const int cb = (threadIdx.x >> 6) * 16;
  #pragma unroll
  for (int i = 0; i < 16; ++i) {
    const int cl = cb + i;
    const int gc = b * CC + c0 + cl;
    float v = x[(size_t)gc * TT + t0 + tl];
    float xn = (v - mean[gc]) * rstd[gc];
    tile[tl][cl] = __float2bfloat16(xn);
  }
  __syncthreads();
  #pragma unroll
  for (int i = 0; i < 16; ++i) {
    const int tl2 = cb + i;
    const int cl2 = tl;
    xnT[((size_t)(b * TT + t0 + tl2)) * CC + c0 + cl2] = tile[tl2][cl2];
  }
}

// ---------------- K2: QKV GEMM  (o,t) tiles, K=C ----------------
// A = w_qkv bf16 [1536][512]; B = xnT [b][t][512]; writes Q,K:[bh][t][64], V:[bh][64][t]
__global__ __launch_bounds__(256) void k_qkv_gemm(const __hip_bfloat16* __restrict__ Wq,
                                                  const __hip_bfloat16* __restrict__ Xt,
                                                  const float* __restrict__ bias,
                                                  __hip_bfloat16* __restrict__ Qb,
                                                  __hip_bfloat16* __restrict__ Kb,
                                                  __hip_bfloat16* __restrict__ Vb) {
  __shared__ __hip_bfloat16 As[128 * 64];
  __shared__ __hip_bfloat16 Bs[128 * 64];
  const int tid  = threadIdx.x;
  const int lane = tid & 63;
  const int wave = tid >> 6;
  const int wr = wave >> 1, wc = wave & 1;
  const int tn0 = blockIdx.x * 128;
  const int om0 = blockIdx.y * 128;
  const int b   = blockIdx.z;

  const __hip_bfloat16* Ab  = Wq + (size_t)om0 * CC;
  const __hip_bfloat16* Bbp = Xt + ((size_t)b * TT + tn0) * CC;

  f32x4 acc[4][4] = {};
  const int l15  = lane & 15;
  const int kgrp = (lane >> 4) << 3;

  for (int k0 = 0; k0 < CC; k0 += 64) {
    #pragma unroll
    for (int r = 0; r < 4; ++r) {
      int idx = r * 256 + tid;
      int row = idx >> 3, ch = (idx & 7) << 3;
      load_lds16(Ab + (size_t)row * CC + k0 + ch, &As[(r * 256 + wave * 64) * 8]);
    }
    #pragma unroll
    for (int r = 0; r < 4; ++r) {
      int idx = r * 256 + tid;
      int row = idx >> 3, ch = (idx & 7) << 3;
      load_lds16(Bbp + (size_t)row * CC + k0 + ch, &Bs[(r * 256 + wave * 64) * 8]);
    }
    __syncthreads();
    #pragma unroll
    for (int kk = 0; kk < 2; ++kk) {
      const int klo = kk * 32 + kgrp;
      bf16x8s af[4], bfr[4];
      #pragma unroll
      for (int mf = 0; mf < 4; ++mf)
        af[mf] = *(const bf16x8s*)&As[(wr * 64 + mf * 16 + l15) * 64 + klo];
      #pragma unroll
      for (int nf = 0; nf < 4; ++nf)
        bfr[nf] = *(const bf16x8s*)&Bs[(wc * 64 + nf * 16 + l15) * 64 + klo];
      #pragma unroll
      for (int mf = 0; mf < 4; ++mf)
        #pragma unroll
        for (int nf = 0; nf < 4; ++nf)
          acc[mf][nf] = __builtin_amdgcn_mfma_f32_16x16x32_bf16(af[mf], bfr[nf], acc[mf][nf], 0, 0, 0);
    }
    __syncthreads();
  }

  const int rg = (lane >> 4) << 2;
  #pragma unroll
  for (int mf = 0; mf < 4; ++mf) {
    #pragma unroll
    for (int j = 0; j < 4; ++j) {
      const int o  = om0 + wr * 64 + mf * 16 + rg + j;
      const int h  = o / 192;
      const int r  = o % 192;
      const int bh = b * NH + h;
      const float bv = bias[o];
      #pragma unroll
      for (int nf = 0; nf < 4; ++nf) {
        const int t = tn0 + wc * 64 + nf * 16 + l15;
        float val = acc[mf][nf][j] + bv;
        if (r < 64)       Qb[((size_t)bh * TT + t) * CHD + r]        = __float2bfloat16(val * 0.125f); // scale^2 folded into Q
        else if (r < 128) Kb[((size_t)bh * TT + t) * CHD + (r - 64)] = __float2bfloat16(val);
        else              Vb[((size_t)bh * CHD + (r - 128)) * TT + t] = __float2bfloat16(val);
      }
    }
  }
}

// ---------------- K4: flash attention, swapped-operand 32x32, LDS-staged K/V ----------------
// Q,K:[bh][t][64], V:[bh][64][t] -> aT[b][t][512]
// QK^T swapped: D[s][q] = mfma(A=K, B=Q^T); each lane owns the full P-row of ONE q.
// PV swapped:  D[d][q] = mfma(A=V^T, B=P^T); m/l/rescale/divide stay lane-local.
// K/V tiles (64x64 bf16 = 8KB each) staged once per block via global_load_lds,
// double-buffered (2-phase pipeline, T3-minimum). LDS layout: linear dest,
// XOR-swizzled SOURCE (rule 21): LDS byte o holds global byte
// (o&~127) | ((o&127) ^ ((row&7)<<4)), row = o>>7. Reads apply the same XOR.
__global__ __launch_bounds__(256) void k_attn(const __hip_bfloat16* __restrict__ Qb,
                                              const __hip_bfloat16* __restrict__ Kb,
                                              const __hip_bfloat16* __restrict__ Vb,
                                              __hip_bfloat16* __restrict__ aT) {
  const int lane = threadIdx.x & 63;
  const int wave = threadIdx.x >> 6;
  const int bh   = blockIdx.y;
  const int q0   = blockIdx.x * 128 + wave * 32;   // 32 q-rows per wave
  const int l31  = lane & 31;
  const int hi8  = (lane >> 5) << 3;

  __shared__ char lds[2][16384];                   // per buf: K tile [0,8K), V tile [8K,16K)

  const __hip_bfloat16* Qh = Qb + (size_t)bh * TT * CHD;
  const __hip_bfloat16* Kh = Kb + (size_t)bh * TT * CHD;
  const __hip_bfloat16* Vh = Vb + (size_t)bh * CHD * TT;

  // stage helper (per-wave share): 2 K-issues + 2 V-issues of 64 lanes x 16B
  auto stage = [&](int buf, int kv0) {
    const char* kg = (const char*)(Kh + (size_t)kv0 * CHD);   // contiguous 8KB
    const char* vg = (const char*)Vh + (size_t)kv0 * 2;       // row stride 2048B
    #pragma unroll
    for (int i = 0; i < 2; ++i) {
      const int slot = wave * 128 + i * 64 + lane;            // 0..511
      const int o = slot * 16;
      const int r = o >> 7;
      const int cs = o & 127;
      const int swc = cs ^ ((r & 7) << 4);
      load_lds16(kg + (o & ~127) + swc, &lds[buf][(wave * 128 + i * 64) * 16]);
      load_lds16(vg + r * 2048 + swc,   &lds[buf][8192 + (wave * 128 + i * 64) * 16]);
    }
  };

  // Q B-frags: lane holds Q[q0+l31][16*dstep + hi8 + j]
  bf16x8s aq[4];
  #pragma unroll
  for (int d = 0; d < 4; ++d)
    aq[d] = *(const bf16x8s*)&Qh[(size_t)(q0 + l31) * CHD + d * 16 + hi8];

  f32x16 oacc0 = {}, oacc1 = {};
  float m_run = -1e30f, l_run = 0.f;

  const int sw = (l31 & 7) << 4;          // read-side XOR (same for rows r and r+32)
  const int cb = hi8 * 2;                 // byte offset of this half's 16B within a 32-col span

  stage(0, 0);
  __syncthreads();                        // drains vmcnt before first reads

  for (int st = 0; st < 16; ++st) {
    const int buf = st & 1;
    if (st < 15) stage(buf ^ 1, (st + 1) * 64);   // async prefetch next tile

    const char* kb = lds[buf];
    const char* vb = lds[buf] + 8192;

    // ---- K frags from LDS (swizzled) ----
    bf16x8s kf0[4], kf1[4];
    #pragma unroll
    for (int d = 0; d < 4; ++d) {
      const int col = d * 32 + cb;
      kf0[d] = *(const bf16x8s*)(kb + l31 * 128        + (col ^ sw));
      kf1[d] = *(const bf16x8s*)(kb + (32 + l31) * 128 + (col ^ sw));
    }

    // ---- QK^T: two 32x32 S-tiles ----
    f32x16 s0 = {}, s1 = {};
    __builtin_amdgcn_s_setprio(1);
    #pragma unroll
    for (int d = 0; d < 4; ++d) {
      s0 = __builtin_amdgcn_mfma_f32_32x32x16_bf16(kf0[d], aq[d], s0, 0, 0, 0);
      s1 = __builtin_amdgcn_mfma_f32_32x32x16_bf16(kf1[d], aq[d], s1, 0, 0, 0);
    }
    __builtin_amdgcn_s_setprio(0);

    // ---- V frags from LDS (independent of softmax; overlaps VALU) ----
    bf16x8s vf0[4], vf1[4];
    #pragma unroll
    for (int ks = 0; ks < 4; ++ks) {
      const int col = ks * 32 + cb;
      vf0[ks] = *(const bf16x8s*)(vb + l31 * 128        + (col ^ sw));
      vf1[ks] = *(const bf16x8s*)(vb + (32 + l31) * 128 + (col ^ sw));
    }

    // ---- row max (tree over 32 local values + one cross-half exchange) ----
    float t16[16];
    #pragma unroll
    for (int i = 0; i < 16; ++i) t16[i] = fmaxf(s0[i], s1[i]);
    float t8[8];
    #pragma unroll
    for (int i = 0; i < 8; ++i) t8[i] = fmaxf(t16[i], t16[i + 8]);
    float t4[4];
    #pragma unroll
    for (int i = 0; i < 4; ++i) t4[i] = fmaxf(t8[i], t8[i + 4]);
    float lmax = fmaxf(fmaxf(t4[0], t4[1]), fmaxf(t4[2], t4[3]));
    float pmax = fmaxf(lmax, __shfl_xor(lmax, 32));

    // ---- defer-max (T13, THR=8): skip rescale when growth small ----
    if (!__all(pmax <= m_run + 8.0f)) {
      const float mnew  = fmaxf(m_run, pmax);
      const float alpha = __expf(m_run - mnew);
      m_run = mnew;
      l_run *= alpha;
      #pragma unroll
      for (int i = 0; i < 16; ++i) { oacc0[i] *= alpha; oacc1[i] *= alpha; }
    }

    // ---- p = exp(s - m), in place; row sum ----
    #pragma unroll
    for (int i = 0; i < 16; ++i) s0[i] = __expf(s0[i] - m_run);
    #pragma unroll
    for (int i = 0; i < 16; ++i) s1[i] = __expf(s1[i] - m_run);
    float a8[8];
    #pragma unroll
    for (int i = 0; i < 8; ++i) a8[i] = (s0[i] + s0[i + 8]) + (s1[i] + s1[i + 8]);
    float a4[4];
    #pragma unroll
    for (int i = 0; i < 4; ++i) a4[i] = a8[i] + a8[i + 4];
    float lsum = (a4[0] + a4[1]) + (a4[2] + a4[3]);
    lsum += __shfl_xor(lsum, 32);
    l_run += lsum;

    // ---- pack P to bf16 words ----
    unsigned int wa[8], wb[8];
    #pragma unroll
    for (int g = 0; g < 4; ++g) {
      wa[g]     = cvtpk_bf16(s0[4 * g + 0], s0[4 * g + 1]);
      wb[g]     = cvtpk_bf16(s0[4 * g + 2], s0[4 * g + 3]);
      wa[g + 4] = cvtpk_bf16(s1[4 * g + 0], s1[4 * g + 1]);
      wb[g + 4] = cvtpk_bf16(s1[4 * g + 2], s1[4 * g + 3]);
    }

    // ---- PV: 4 k-steps x 2 d-blocks ----
    __builtin_amdgcn_s_setprio(1);
    #pragma unroll
    for (int ks = 0; ks < 4; ++ks) {
      unsigned int x0, y0, x1, y1;
      plswap(wa[2 * ks], wa[2 * ks + 1], x0, y0);
      plswap(wb[2 * ks], wb[2 * ks + 1], x1, y1);
      bf16x8s pf = __builtin_bit_cast(bf16x8s, (u32x4){x0, x1, y0, y1});
      oacc0 = __builtin_amdgcn_mfma_f32_32x32x16_bf16(vf0[ks], pf, oacc0, 0, 0, 0);
      oacc1 = __builtin_amdgcn_mfma_f32_32x32x16_bf16(vf1[ks], pf, oacc1, 0, 0, 0);
    }
    __builtin_amdgcn_s_setprio(0);

    __syncthreads();   // drains vmcnt (prefetch done) + all waves done reading buf
  }

  // ---- epilogue: O[d][q] / l -> aT[b][t=q][h*64+d]; lane writes 8B chunks ----
  const int b = bh >> 3, h = bh & 7;
  const float rl = 1.0f / l_run;
  const int t = q0 + l31;
  __hip_bfloat16* arow = aT + ((size_t)(b * TT + t)) * CC + h * CHD;
  const int hi4 = hi8 >> 1;
  #pragma unroll
  for (int rr = 0; rr < 4; ++rr) {
    {
      const int c0 = rr * 8 + hi4;
      unsigned int lo = cvtpk_bf16(oacc0[4 * rr + 0] * rl, oacc0[4 * rr + 1] * rl);
      unsigned int hw = cvtpk_bf16(oacc0[4 * rr + 2] * rl, oacc0[4 * rr + 3] * rl);
      *(uint2*)&arow[c0] = make_uint2(lo, hw);
    }
    {
      const int c0 = 32 + rr * 8 + hi4;
      unsigned int lo = cvtpk_bf16(oacc1[4 * rr + 0] * rl, oacc1[4 * rr + 1] * rl);
      unsigned int hw = cvtpk_bf16(oacc1[4 * rr + 2] * rl, oacc1[4 * rr + 3] * rl);
      *(uint2*)&arow[c0] = make_uint2(lo, hw);
    }
  }
}

// ---------------- K5: proj GEMM + bias + xn residual ----------------
__global__ __launch_bounds__(256) void k_proj_gemm(const __hip_bfloat16* __restrict__ Wp,
                                                   const __hip_bfloat16* __restrict__ At,
                                                   const float* __restrict__ bias,
                                                   const float* __restrict__ x,
                                                   const float* __restrict__ mean,
                                                   const float* __restrict__ rstd,
                                                   float* __restrict__ out) {
  __shared__ __hip_bfloat16 As[128 * 64];
  __shared__ __hip_bfloat16 Bs[128 * 64];
  const int tid  = threadIdx.x;
  const int lane = tid & 63;
  const int wave = tid >> 6;
  const int wr = wave >> 1, wc = wave & 1;
  const int tn0 = blockIdx.x * 128;
  const int om0 = blockIdx.y * 128;
  const int b   = blockIdx.z;

  const __hip_bfloat16* Ab  = Wp + (size_t)om0 * CC;
  const __hip_bfloat16* Bbp = At + ((size_t)b * TT + tn0) * CC;

  f32x4 acc[4][4] = {};
  const int l15  = lane & 15;
  const int kgrp = (lane >> 4) << 3;

  for (int k0 = 0; k0 < CC; k0 += 64) {
    #pragma unroll
    for (int r = 0; r < 4; ++r) {
      int idx = r * 256 + tid;
      int row = idx >> 3, ch = (idx & 7) << 3;
      load_lds16(Ab + (size_t)row * CC + k0 + ch, &As[(r * 256 + wave * 64) * 8]);
    }
    #pragma unroll
    for (int r = 0; r < 4; ++r) {
      int idx = r * 256 + tid;
      int row = idx >> 3, ch = (idx & 7) << 3;
      load_lds16(Bbp + (size_t)row * CC + k0 + ch, &Bs[(r * 256 + wave * 64) * 8]);
    }
    __syncthreads();
    #pragma unroll
    for (int kk = 0; kk < 2; ++kk) {
      const int klo = kk * 32 + kgrp;
      bf16x8s af[4], bfr[4];
      #pragma unroll
      for (int mf = 0; mf < 4; ++mf)
        af[mf] = *(const bf16x8s*)&As[(wr * 64 + mf * 16 + l15) * 64 + klo];
      #pragma unroll
      for (int nf = 0; nf < 4; ++nf)
        bfr[nf] = *(const bf16x8s*)&Bs[(wc * 64 + nf * 16 + l15) * 64 + klo];
      #pragma unroll
      for (int mf = 0; mf < 4; ++mf)
        #pragma unroll
        for (int nf = 0; nf < 4; ++nf)
          acc[mf][nf] = __builtin_amdgcn_mfma_f32_16x16x32_bf16(af[mf], bfr[nf], acc[mf][nf], 0, 0, 0);
    }
    __syncthreads();
  }

  const int rg = (lane >> 4) << 2;
  #pragma unroll
  for (int mf = 0; mf < 4; ++mf) {
    #pragma unroll
    for (int j = 0; j < 4; ++j) {
      const int o = om0 + wr * 64 + mf * 16 + rg + j;
      const int gco = b * CC + o;
      const float bv = bias[o];
      const float mu = mean[gco], rs = rstd[gco];
      #pragma unroll
      for (int nf = 0; nf < 4; ++nf) {
        const int t = tn0 + wc * 64 + nf * 16 + l15;
        const size_t xi = (size_t)gco * TT + t;
        float xn = (x[xi] - mu) * rs;
        out[xi] = xn + acc[mf][nf][j] + bv;
      }
    }
  }
}

extern "C" void kernel_launch(void* const* d_in, const int* in_sizes, int n_in,
                              void* d_out, int out_size, void* d_ws, size_t ws_size,
                              hipStream_t stream) {
  const float* x  = (const float*)d_in[0];
  const float* wq = (const float*)d_in[1];
  const float* bq = (const float*)d_in[2];
  const float* wp = (const float*)d_in[3];
  const float* bp = (const float*)d_in[4];
  float* out = (float*)d_out;

  char* ws = (char*)d_ws;
  __hip_bfloat16* wqb = (__hip_bfloat16*)(ws);                  // 1536*512*2      = 1,572,864
  __hip_bfloat16* wpb = (__hip_bfloat16*)(ws + 1572864);        // 512*512*2       =   524,288
  float*          mean = (float*)(ws + 2097152);                // 8192*4
  float*          rstd = (float*)(ws + 2129920);                // 8192*4
  __hip_bfloat16* xnT = (__hip_bfloat16*)(ws + 2162688);        // 16*1024*512*2   = 16,777,216
  __hip_bfloat16* Qb  = (__hip_bfloat16*)(ws + 18939904);       // 128*1024*64*2
  __hip_bfloat16* Kb  = (__hip_bfloat16*)(ws + 35717120);
  __hip_bfloat16* Vb  = (__hip_bfloat16*)(ws + 52494336);       // ends 69,271,552
  __hip_bfloat16* aT  = xnT;   // alias: xnT fully consumed by k_qkv_gemm before k_attn writes aT

  k_convert_w<<<4096, 256, 0, stream>>>(wq, wp, wqb, wpb);
  k_ln_stats<<<BB * CC, 256, 0, stream>>>(x, mean, rstd);
  k_normT<<<dim3(TT / 64, CC / 64, BB), 256, 0, stream>>>(x, mean, rstd, xnT);
  k_qkv_gemm<<<dim3(TT / 128, OQ / 128, BB), 256, 0, stream>>>(wqb, xnT, bq, Qb, Kb, Vb);
  k_attn<<<dim3(TT / 128, BB * NH), 256, 0, stream>>>(Qb, Kb, Vb, aT);
  k_proj_gemm<<<dim3(TT / 128, CC / 128, BB), 256, 0, stream>>>(wpb, aT, bp, x, mean, rstd, out);
}

// Round 5
// 248.870 us; speedup vs baseline: 1.6893x; 1.0051x over previous
//
#include <hip/hip_runtime.h>
#include <hip/hip_bf16.h>

using bf16x8s = __attribute__((ext_vector_type(8))) short;
using f32x4   = __attribute__((ext_vector_type(4))) float;
using f32x16  = __attribute__((ext_vector_type(16))) float;
using u32x4   = __attribute__((ext_vector_type(4))) unsigned int;

#define DEVI __device__ __forceinline__

static constexpr int BB  = 16;    // batch
static constexpr int CC  = 512;   // channels
static constexpr int TT  = 1024;  // tokens = 32*32
static constexpr int OQ  = 1536;  // 3*C
static constexpr int NH  = 8;     // heads
static constexpr int CHD = 64;    // head dim

DEVI void load_lds16(const void* g, void* l) {
  __builtin_amdgcn_global_load_lds((const __attribute__((address_space(1))) void*)g,
                                   (__attribute__((address_space(3))) void*)l,
                                   16, 0, 0);
}

DEVI unsigned int cvtpk_bf16(float lo, float hi) {
  unsigned int r;
  asm("v_cvt_pk_bf16_f32 %0, %1, %2" : "=v"(r) : "v"(lo), "v"(hi));
  return r;
}

// permlane32_swap(a,b): x = (lane>=32 ? b-of-partner : own a); y = (lane>=32 ? own b : a-of-partner)
DEVI void plswap(unsigned int a, unsigned int b, unsigned int& x, unsigned int& y) {
#if __has_builtin(__builtin_amdgcn_permlane32_swap)
  auto r = __builtin_amdgcn_permlane32_swap((int)a, (int)b, false, false);
  x = (unsigned int)r[0];
  y = (unsigned int)r[1];
#else
  unsigned int pa = (unsigned int)__shfl_xor((int)a, 32);
  unsigned int pb = (unsigned int)__shfl_xor((int)b, 32);
  const bool hi = (threadIdx.x & 32) != 0;
  x = hi ? pb : a;
  y = hi ? b : pa;
#endif
}

// ---------------- K0: convert weights fp32 -> bf16 ----------------
__global__ __launch_bounds__(256) void k_convert_w(const float* __restrict__ wq,
                                                   const float* __restrict__ wp,
                                                   __hip_bfloat16* __restrict__ wqb,
                                                   __hip_bfloat16* __restrict__ wpb) {
  int i = blockIdx.x * 256 + threadIdx.x;
  const int NQ = OQ * CC;                 // 786432
  if (i < NQ) wqb[i] = __float2bfloat16(wq[i]);
  else        wpb[i - NQ] = __float2bfloat16(wp[i - NQ]);   // grid covers NQ + 512*512 exactly
}

// ---------------- K1a: LayerNorm stats per (b,c) over T ----------------
__global__ __launch_bounds__(256) void k_ln_stats(const float* __restrict__ x,
                                                  float* __restrict__ mean,
                                                  float* __restrict__ rstd) {
  const int row = blockIdx.x;                    // b*C + c
  const float4* xv = (const float4*)(x + (size_t)row * TT);
  float4 v = xv[threadIdx.x];
  float s = v.x + v.y + v.z + v.w;
  float q = v.x * v.x + v.y * v.y + v.z * v.z + v.w * v.w;
  #pragma unroll
  for (int off = 1; off < 64; off <<= 1) {
    s += __shfl_xor(s, off);
    q += __shfl_xor(q, off);
  }
  __shared__ float ss[4], sq[4];
  const int wave = threadIdx.x >> 6;
  if ((threadIdx.x & 63) == 0) { ss[wave] = s; sq[wave] = q; }
  __syncthreads();
  if (threadIdx.x == 0) {
    float S = ss[0] + ss[1] + ss[2] + ss[3];
    float Q = sq[0] + sq[1] + sq[2] + sq[3];
    float m = S * (1.0f / TT);
    float var = Q * (1.0f / TT) - m * m;
    mean[row] = m;
    rstd[row] = 1.0f / sqrtf(var + 1e-5f);
  }
}

// ---------------- K1b: normalize + transpose -> xnT[b][t][c] bf16 ----------------
__global__ __launch_bounds__(256) void k_normT(const float* __restrict__ x,
                                               const float* __restrict__ mean,
                                               const float* __restrict__ rstd,
                                               __hip_bfloat16* __restrict__ xnT) {
  const int t0 = blockIdx.x * 64;
  const int c0 = blockIdx.y * 64;
  const int b  = blockIdx.z;
  __shared__ __hip_bfloat16 tile[64][66];        // stride 66 elems = 132B: conflict-free
  const int tl = threadIdx.x & 63;
  const int cb = (threadIdx.x >> 6) * 16;
  #pragma unroll
  for (int i = 0; i < 16; ++i) {
    const int cl = cb + i;
    const int gc = b * CC + c0 + cl;
    float v = x[(size_t)gc * TT + t0 + tl];
    float xn = (v - mean[gc]) * rstd[gc];
    tile[tl][cl] = __float2bfloat16(xn);
  }
  __syncthreads();
  #pragma unroll
  for (int i = 0; i < 16; ++i) {
    const int tl2 = cb + i;
    const int cl2 = tl;
    xnT[((size_t)(b * TT + t0 + tl2)) * CC + c0 + cl2] = tile[tl2][cl2];
  }
}

// ======== shared GEMM core pieces (128x128 tile, BK=32, dbuf, swizzled) ========
// LDS tile: [128 rows][32 cols] bf16, row stride 64B. Swizzle involution on the
// 16B chunk: byte c (0..63) -> c ^ (((row>>1)&3)<<4). Gives 8 distinct 16B slots
// per 128B bank span -> 2-way conflict (free). Stage: linear LDS dest +
// inverse-swizzled per-lane global source (rule 21).

// ---------------- K2: QKV GEMM  (o,t) tiles, K=C ----------------
// A = w_qkv bf16 [1536][512]; B = xnT [b][t][512]; writes Q,K:[bh][t][64], V:[bh][64][t]
__global__ __launch_bounds__(256) void k_qkv_gemm(const __hip_bfloat16* __restrict__ Wq,
                                                  const __hip_bfloat16* __restrict__ Xt,
                                                  const float* __restrict__ bias,
                                                  __hip_bfloat16* __restrict__ Qb,
                                                  __hip_bfloat16* __restrict__ Kb,
                                                  __hip_bfloat16* __restrict__ Vb) {
  __shared__ __hip_bfloat16 As2[2][128 * 32];
  __shared__ __hip_bfloat16 Bs2[2][128 * 32];
  const int tid  = threadIdx.x;
  const int lane = tid & 63;
  const int wave = tid >> 6;
  const int wr = wave >> 1, wc = wave & 1;
  const int tn0 = blockIdx.x * 128;
  const int om0 = blockIdx.y * 128;
  const int b   = blockIdx.z;

  const char* Ab  = (const char*)(Wq + (size_t)om0 * CC);
  const char* Bbp = (const char*)(Xt + ((size_t)b * TT + tn0) * CC);

  f32x4 acc[4][4] = {};
  const int l15  = lane & 15;
  const int frc  = ((lane >> 4) << 3) * 2;        // frag col byte: 0,16,32,48
  const int rsw  = ((l15 >> 1) & 3) << 4;         // read-side XOR (row bits 1-2)

  // per-thread stage geometry: slot = i*256+tid -> o = slot*16; r=o>>6, c=o&63
  int srow[2], scsw[2], sdst[2];
  #pragma unroll
  for (int i = 0; i < 2; ++i) {
    const int o = (i * 256 + tid) * 16;
    const int r = o >> 6, c = o & 63;
    srow[i] = r;
    scsw[i] = c ^ (((r >> 1) & 3) << 4);
    sdst[i] = (i * 256 + wave * 64) * 16;         // wave-uniform dest base (bytes)
  }

  auto stage = [&](int buf, int k0) {
    const int kb = k0 * 2;
    #pragma unroll
    for (int i = 0; i < 2; ++i) {
      load_lds16(Ab  + (size_t)srow[i] * 1024 + kb + scsw[i], (char*)As2[buf] + sdst[i]);
      load_lds16(Bbp + (size_t)srow[i] * 1024 + kb + scsw[i], (char*)Bs2[buf] + sdst[i]);
    }
  };

  stage(0, 0);
  __syncthreads();

  for (int kt = 0; kt < 16; ++kt) {
    const int buf = kt & 1;
    if (kt < 15) stage(buf ^ 1, (kt + 1) * 32);

    const char* Asb = (const char*)As2[buf];
    const char* Bsb = (const char*)Bs2[buf];
    bf16x8s af[4], bfr[4];
    #pragma unroll
    for (int mf = 0; mf < 4; ++mf)
      af[mf] = *(const bf16x8s*)(Asb + (wr * 64 + mf * 16 + l15) * 64 + (frc ^ rsw));
    #pragma unroll
    for (int nf = 0; nf < 4; ++nf)
      bfr[nf] = *(const bf16x8s*)(Bsb + (wc * 64 + nf * 16 + l15) * 64 + (frc ^ rsw));
    #pragma unroll
    for (int mf = 0; mf < 4; ++mf)
      #pragma unroll
      for (int nf = 0; nf < 4; ++nf)
        acc[mf][nf] = __builtin_amdgcn_mfma_f32_16x16x32_bf16(af[mf], bfr[nf], acc[mf][nf], 0, 0, 0);

    __syncthreads();   // drains lgkm (reads of buf done) + vmcnt (prefetch landed)
  }

  const int rg = (lane >> 4) << 2;
  #pragma unroll
  for (int mf = 0; mf < 4; ++mf) {
    #pragma unroll
    for (int j = 0; j < 4; ++j) {
      const int o  = om0 + wr * 64 + mf * 16 + rg + j;
      const int h  = o / 192;
      const int r  = o % 192;
      const int bh = b * NH + h;
      const float bv = bias[o];
      #pragma unroll
      for (int nf = 0; nf < 4; ++nf) {
        const int t = tn0 + wc * 64 + nf * 16 + l15;
        float val = acc[mf][nf][j] + bv;
        if (r < 64)       Qb[((size_t)bh * TT + t) * CHD + r]        = __float2bfloat16(val * 0.125f); // scale^2 folded into Q
        else if (r < 128) Kb[((size_t)bh * TT + t) * CHD + (r - 64)] = __float2bfloat16(val);
        else              Vb[((size_t)bh * CHD + (r - 128)) * TT + t] = __float2bfloat16(val);
      }
    }
  }
}

// ---------------- K4: flash attention, swapped-operand 32x32, LDS-staged K/V ----------------
// (unchanged from R4 — validated: bank conflicts ~0, off the critical top-5)
__global__ __launch_bounds__(256) void k_attn(const __hip_bfloat16* __restrict__ Qb,
                                              const __hip_bfloat16* __restrict__ Kb,
                                              const __hip_bfloat16* __restrict__ Vb,
                                              __hip_bfloat16* __restrict__ aT) {
  const int lane = threadIdx.x & 63;
  const int wave = threadIdx.x >> 6;
  const int bh   = blockIdx.y;
  const int q0   = blockIdx.x * 128 + wave * 32;   // 32 q-rows per wave
  const int l31  = lane & 31;
  const int hi8  = (lane >> 5) << 3;

  __shared__ char lds[2][16384];                   // per buf: K tile [0,8K), V tile [8K,16K)

  const __hip_bfloat16* Qh = Qb + (size_t)bh * TT * CHD;
  const __hip_bfloat16* Kh = Kb + (size_t)bh * TT * CHD;
  const __hip_bfloat16* Vh = Vb + (size_t)bh * CHD * TT;

  auto stage = [&](int buf, int kv0) {
    const char* kg = (const char*)(Kh + (size_t)kv0 * CHD);   // contiguous 8KB
    const char* vg = (const char*)Vh + (size_t)kv0 * 2;       // row stride 2048B
    #pragma unroll
    for (int i = 0; i < 2; ++i) {
      const int slot = wave * 128 + i * 64 + lane;            // 0..511
      const int o = slot * 16;
      const int r = o >> 7;
      const int cs = o & 127;
      const int swc = cs ^ ((r & 7) << 4);
      load_lds16(kg + (o & ~127) + swc, &lds[buf][(wave * 128 + i * 64) * 16]);
      load_lds16(vg + r * 2048 + swc,   &lds[buf][8192 + (wave * 128 + i * 64) * 16]);
    }
  };

  bf16x8s aq[4];
  #pragma unroll
  for (int d = 0; d < 4; ++d)
    aq[d] = *(const bf16x8s*)&Qh[(size_t)(q0 + l31) * CHD + d * 16 + hi8];

  f32x16 oacc0 = {}, oacc1 = {};
  float m_run = -1e30f, l_run = 0.f;

  const int sw = (l31 & 7) << 4;          // read-side XOR (same for rows r and r+32)
  const int cb = hi8 * 2;                 // byte offset of this half's 16B within a 32-col span

  stage(0, 0);
  __syncthreads();                        // drains vmcnt before first reads

  for (int st = 0; st < 16; ++st) {
    const int buf = st & 1;
    if (st < 15) stage(buf ^ 1, (st + 1) * 64);   // async prefetch next tile

    const char* kb = lds[buf];
    const char* vb = lds[buf] + 8192;

    bf16x8s kf0[4], kf1[4];
    #pragma unroll
    for (int d = 0; d < 4; ++d) {
      const int col = d * 32 + cb;
      kf0[d] = *(const bf16x8s*)(kb + l31 * 128        + (col ^ sw));
      kf1[d] = *(const bf16x8s*)(kb + (32 + l31) * 128 + (col ^ sw));
    }

    f32x16 s0 = {}, s1 = {};
    __builtin_amdgcn_s_setprio(1);
    #pragma unroll
    for (int d = 0; d < 4; ++d) {
      s0 = __builtin_amdgcn_mfma_f32_32x32x16_bf16(kf0[d], aq[d], s0, 0, 0, 0);
      s1 = __builtin_amdgcn_mfma_f32_32x32x16_bf16(kf1[d], aq[d], s1, 0, 0, 0);
    }
    __builtin_amdgcn_s_setprio(0);

    bf16x8s vf0[4], vf1[4];
    #pragma unroll
    for (int ks = 0; ks < 4; ++ks) {
      const int col = ks * 32 + cb;
      vf0[ks] = *(const bf16x8s*)(vb + l31 * 128        + (col ^ sw));
      vf1[ks] = *(const bf16x8s*)(vb + (32 + l31) * 128 + (col ^ sw));
    }

    float t16[16];
    #pragma unroll
    for (int i = 0; i < 16; ++i) t16[i] = fmaxf(s0[i], s1[i]);
    float t8[8];
    #pragma unroll
    for (int i = 0; i < 8; ++i) t8[i] = fmaxf(t16[i], t16[i + 8]);
    float t4[4];
    #pragma unroll
    for (int i = 0; i < 4; ++i) t4[i] = fmaxf(t8[i], t8[i + 4]);
    float lmax = fmaxf(fmaxf(t4[0], t4[1]), fmaxf(t4[2], t4[3]));
    float pmax = fmaxf(lmax, __shfl_xor(lmax, 32));

    if (!__all(pmax <= m_run + 8.0f)) {
      const float mnew  = fmaxf(m_run, pmax);
      const float alpha = __expf(m_run - mnew);
      m_run = mnew;
      l_run *= alpha;
      #pragma unroll
      for (int i = 0; i < 16; ++i) { oacc0[i] *= alpha; oacc1[i] *= alpha; }
    }

    #pragma unroll
    for (int i = 0; i < 16; ++i) s0[i] = __expf(s0[i] - m_run);
    #pragma unroll
    for (int i = 0; i < 16; ++i) s1[i] = __expf(s1[i] - m_run);
    float a8[8];
    #pragma unroll
    for (int i = 0; i < 8; ++i) a8[i] = (s0[i] + s0[i + 8]) + (s1[i] + s1[i + 8]);
    float a4[4];
    #pragma unroll
    for (int i = 0; i < 4; ++i) a4[i] = a8[i] + a8[i + 4];
    float lsum = (a4[0] + a4[1]) + (a4[2] + a4[3]);
    lsum += __shfl_xor(lsum, 32);
    l_run += lsum;

    unsigned int wa[8], wb[8];
    #pragma unroll
    for (int g = 0; g < 4; ++g) {
      wa[g]     = cvtpk_bf16(s0[4 * g + 0], s0[4 * g + 1]);
      wb[g]     = cvtpk_bf16(s0[4 * g + 2], s0[4 * g + 3]);
      wa[g + 4] = cvtpk_bf16(s1[4 * g + 0], s1[4 * g + 1]);
      wb[g + 4] = cvtpk_bf16(s1[4 * g + 2], s1[4 * g + 3]);
    }

    __builtin_amdgcn_s_setprio(1);
    #pragma unroll
    for (int ks = 0; ks < 4; ++ks) {
      unsigned int x0, y0, x1, y1;
      plswap(wa[2 * ks], wa[2 * ks + 1], x0, y0);
      plswap(wb[2 * ks], wb[2 * ks + 1], x1, y1);
      bf16x8s pf = __builtin_bit_cast(bf16x8s, (u32x4){x0, x1, y0, y1});
      oacc0 = __builtin_amdgcn_mfma_f32_32x32x16_bf16(vf0[ks], pf, oacc0, 0, 0, 0);
      oacc1 = __builtin_amdgcn_mfma_f32_32x32x16_bf16(vf1[ks], pf, oacc1, 0, 0, 0);
    }
    __builtin_amdgcn_s_setprio(0);

    __syncthreads();
  }

  const int b = bh >> 3, h = bh & 7;
  const float rl = 1.0f / l_run;
  const int t = q0 + l31;
  __hip_bfloat16* arow = aT + ((size_t)(b * TT + t)) * CC + h * CHD;
  const int hi4 = hi8 >> 1;
  #pragma unroll
  for (int rr = 0; rr < 4; ++rr) {
    {
      const int c0 = rr * 8 + hi4;
      unsigned int lo = cvtpk_bf16(oacc0[4 * rr + 0] * rl, oacc0[4 * rr + 1] * rl);
      unsigned int hw = cvtpk_bf16(oacc0[4 * rr + 2] * rl, oacc0[4 * rr + 3] * rl);
      *(uint2*)&arow[c0] = make_uint2(lo, hw);
    }
    {
      const int c0 = 32 + rr * 8 + hi4;
      unsigned int lo = cvtpk_bf16(oacc1[4 * rr + 0] * rl, oacc1[4 * rr + 1] * rl);
      unsigned int hw = cvtpk_bf16(oacc1[4 * rr + 2] * rl, oacc1[4 * rr + 3] * rl);
      *(uint2*)&arow[c0] = make_uint2(lo, hw);
    }
  }
}

// ---------------- K5: proj GEMM + bias + xn residual ----------------
__global__ __launch_bounds__(256) void k_proj_gemm(const __hip_bfloat16* __restrict__ Wp,
                                                   const __hip_bfloat16* __restrict__ At,
                                                   const float* __restrict__ bias,
                                                   const float* __restrict__ x,
                                                   const float* __restrict__ mean,
                                                   const float* __restrict__ rstd,
                                                   float* __restrict__ out) {
  __shared__ __hip_bfloat16 As2[2][128 * 32];
  __shared__ __hip_bfloat16 Bs2[2][128 * 32];
  const int tid  = threadIdx.x;
  const int lane = tid & 63;
  const int wave = tid >> 6;
  const int wr = wave >> 1, wc = wave & 1;
  const int tn0 = blockIdx.x * 128;
  const int om0 = blockIdx.y * 128;
  const int b   = blockIdx.z;

  const char* Ab  = (const char*)(Wp + (size_t)om0 * CC);
  const char* Bbp = (const char*)(At + ((size_t)b * TT + tn0) * CC);

  f32x4 acc[4][4] = {};
  const int l15  = lane & 15;
  const int frc  = ((lane >> 4) << 3) * 2;
  const int rsw  = ((l15 >> 1) & 3) << 4;

  int srow[2], scsw[2], sdst[2];
  #pragma unroll
  for (int i = 0; i < 2; ++i) {
    const int o = (i * 256 + tid) * 16;
    const int r = o >> 6, c = o & 63;
    srow[i] = r;
    scsw[i] = c ^ (((r >> 1) & 3) << 4);
    sdst[i] = (i * 256 + wave * 64) * 16;
  }

  auto stage = [&](int buf, int k0) {
    const int kb = k0 * 2;
    #pragma unroll
    for (int i = 0; i < 2; ++i) {
      load_lds16(Ab  + (size_t)srow[i] * 1024 + kb + scsw[i], (char*)As2[buf] + sdst[i]);
      load_lds16(Bbp + (size_t)srow[i] * 1024 + kb + scsw[i], (char*)Bs2[buf] + sdst[i]);
    }
  };

  stage(0, 0);
  __syncthreads();

  for (int kt = 0; kt < 16; ++kt) {
    const int buf = kt & 1;
    if (kt < 15) stage(buf ^ 1, (kt + 1) * 32);

    const char* Asb = (const char*)As2[buf];
    const char* Bsb = (const char*)Bs2[buf];
    bf16x8s af[4], bfr[4];
    #pragma unroll
    for (int mf = 0; mf < 4; ++mf)
      af[mf] = *(const bf16x8s*)(Asb + (wr * 64 + mf * 16 + l15) * 64 + (frc ^ rsw));
    #pragma unroll
    for (int nf = 0; nf < 4; ++nf)
      bfr[nf] = *(const bf16x8s*)(Bsb + (wc * 64 + nf * 16 + l15) * 64 + (frc ^ rsw));
    #pragma unroll
    for (int mf = 0; mf < 4; ++mf)
      #pragma unroll
      for (int nf = 0; nf < 4; ++nf)
        acc[mf][nf] = __builtin_amdgcn_mfma_f32_16x16x32_bf16(af[mf], bfr[nf], acc[mf][nf], 0, 0, 0);

    __syncthreads();
  }

  const int rg = (lane >> 4) << 2;
  #pragma unroll
  for (int mf = 0; mf < 4; ++mf) {
    #pragma unroll
    for (int j = 0; j < 4; ++j) {
      const int o = om0 + wr * 64 + mf * 16 + rg + j;
      const int gco = b * CC + o;
      const float bv = bias[o];
      const float mu = mean[gco], rs = rstd[gco];
      #pragma unroll
      for (int nf = 0; nf < 4; ++nf) {
        const int t = tn0 + wc * 64 + nf * 16 + l15;
        const size_t xi = (size_t)gco * TT + t;
        float xn = (x[xi] - mu) * rs;
        out[xi] = xn + acc[mf][nf][j] + bv;
      }
    }
  }
}

extern "C" void kernel_launch(void* const* d_in, const int* in_sizes, int n_in,
                              void* d_out, int out_size, void* d_ws, size_t ws_size,
                              hipStream_t stream) {
  const float* x  = (const float*)d_in[0];
  const float* wq = (const float*)d_in[1];
  const float* bq = (const float*)d_in[2];
  const float* wp = (const float*)d_in[3];
  const float* bp = (const float*)d_in[4];
  float* out = (float*)d_out;

  char* ws = (char*)d_ws;
  __hip_bfloat16* wqb = (__hip_bfloat16*)(ws);                  // 1536*512*2      = 1,572,864
  __hip_bfloat16* wpb = (__hip_bfloat16*)(ws + 1572864);        // 512*512*2       =   524,288
  float*          mean = (float*)(ws + 2097152);                // 8192*4
  float*          rstd = (float*)(ws + 2129920);                // 8192*4
  __hip_bfloat16* xnT = (__hip_bfloat16*)(ws + 2162688);        // 16*1024*512*2   = 16,777,216
  __hip_bfloat16* Qb  = (__hip_bfloat16*)(ws + 18939904);       // 128*1024*64*2
  __hip_bfloat16* Kb  = (__hip_bfloat16*)(ws + 35717120);
  __hip_bfloat16* Vb  = (__hip_bfloat16*)(ws + 52494336);       // ends 69,271,552
  __hip_bfloat16* aT  = xnT;   // alias: xnT fully consumed by k_qkv_gemm before k_attn writes aT

  k_convert_w<<<4096, 256, 0, stream>>>(wq, wp, wqb, wpb);
  k_ln_stats<<<BB * CC, 256, 0, stream>>>(x, mean, rstd);
  k_normT<<<dim3(TT / 64, CC / 64, BB), 256, 0, stream>>>(x, mean, rstd, xnT);
  k_qkv_gemm<<<dim3(TT / 128, OQ / 128, BB), 256, 0, stream>>>(wqb, xnT, bq, Qb, Kb, Vb);
  k_attn<<<dim3(TT / 128, BB * NH), 256, 0, stream>>>(Qb, Kb, Vb, aT);
  k_proj_gemm<<<dim3(TT / 128, CC / 128, BB), 256, 0, stream>>>(wpb, aT, bp, x, mean, rstd, out);
}

// Round 6
// 224.267 us; speedup vs baseline: 1.8747x; 1.1097x over previous
//
#include <hip/hip_runtime.h>
#include <hip/hip_bf16.h>

using bf16x8s = __attribute__((ext_vector_type(8))) short;
using f32x4   = __attribute__((ext_vector_type(4))) float;
using f32x16  = __attribute__((ext_vector_type(16))) float;
using u32x4   = __attribute__((ext_vector_type(4))) unsigned int;

#define DEVI __device__ __forceinline__

static constexpr int BB  = 16;    // batch
static constexpr int CC  = 512;   // channels
static constexpr int TT  = 1024;  // tokens = 32*32
static constexpr int OQ  = 1536;  // 3*C
static constexpr int NH  = 8;     // heads
static constexpr int CHD = 64;    // head dim

DEVI void load_lds16(const void* g, void* l) {
  __builtin_amdgcn_global_load_lds((const __attribute__((address_space(1))) void*)g,
                                   (__attribute__((address_space(3))) void*)l,
                                   16, 0, 0);
}

DEVI unsigned int cvtpk_bf16(float lo, float hi) {
  unsigned int r;
  asm("v_cvt_pk_bf16_f32 %0, %1, %2" : "=v"(r) : "v"(lo), "v"(hi));
  return r;
}

// permlane32_swap(a,b): x = (lane>=32 ? b-of-partner : own a); y = (lane>=32 ? own b : a-of-partner)
DEVI void plswap(unsigned int a, unsigned int b, unsigned int& x, unsigned int& y) {
#if __has_builtin(__builtin_amdgcn_permlane32_swap)
  auto r = __builtin_amdgcn_permlane32_swap((int)a, (int)b, false, false);
  x = (unsigned int)r[0];
  y = (unsigned int)r[1];
#else
  unsigned int pa = (unsigned int)__shfl_xor((int)a, 32);
  unsigned int pb = (unsigned int)__shfl_xor((int)b, 32);
  const bool hi = (threadIdx.x & 32) != 0;
  x = hi ? pb : a;
  y = hi ? b : pa;
#endif
}

// ---------------- K0: convert weights fp32 -> bf16 ----------------
__global__ __launch_bounds__(256) void k_convert_w(const float* __restrict__ wq,
                                                   const float* __restrict__ wp,
                                                   __hip_bfloat16* __restrict__ wqb,
                                                   __hip_bfloat16* __restrict__ wpb) {
  int i = blockIdx.x * 256 + threadIdx.x;
  const int NQ = OQ * CC;                 // 786432
  if (i < NQ) wqb[i] = __float2bfloat16(wq[i]);
  else        wpb[i - NQ] = __float2bfloat16(wp[i - NQ]);   // grid covers NQ + 512*512 exactly
}

// ---------------- K1a: LayerNorm stats per (b,c) over T ----------------
__global__ __launch_bounds__(256) void k_ln_stats(const float* __restrict__ x,
                                                  float* __restrict__ mean,
                                                  float* __restrict__ rstd) {
  const int row = blockIdx.x;                    // b*C + c
  const float4* xv = (const float4*)(x + (size_t)row * TT);
  float4 v = xv[threadIdx.x];
  float s = v.x + v.y + v.z + v.w;
  float q = v.x * v.x + v.y * v.y + v.z * v.z + v.w * v.w;
  #pragma unroll
  for (int off = 1; off < 64; off <<= 1) {
    s += __shfl_xor(s, off);
    q += __shfl_xor(q, off);
  }
  __shared__ float ss[4], sq[4];
  const int wave = threadIdx.x >> 6;
  if ((threadIdx.x & 63) == 0) { ss[wave] = s; sq[wave] = q; }
  __syncthreads();
  if (threadIdx.x == 0) {
    float S = ss[0] + ss[1] + ss[2] + ss[3];
    float Q = sq[0] + sq[1] + sq[2] + sq[3];
    float m = S * (1.0f / TT);
    float var = Q * (1.0f / TT) - m * m;
    mean[row] = m;
    rstd[row] = 1.0f / sqrtf(var + 1e-5f);
  }
}

// ---------------- K1b: normalize + transpose -> xnT[b][t][c] bf16 ----------------
__global__ __launch_bounds__(256) void k_normT(const float* __restrict__ x,
                                               const float* __restrict__ mean,
                                               const float* __restrict__ rstd,
                                               __hip_bfloat16* __restrict__ xnT) {
  const int t0 = blockIdx.x * 64;
  const int c0 = blockIdx.y * 64;
  const int b  = blockIdx.z;
  __shared__ __hip_bfloat16 tile[64][66];        // stride 66 elems = 132B: conflict-free
  const int tl = threadIdx.x & 63;
  const int cb = (threadIdx.x >> 6) * 16;
  #pragma unroll
  for (int i = 0; i < 16; ++i) {
    const int cl = cb + i;
    const int gc = b * CC + c0 + cl;
    float v = x[(size_t)gc * TT + t0 + tl];
    float xn = (v - mean[gc]) * rstd[gc];
    tile[tl][cl] = __float2bfloat16(xn);
  }
  __syncthreads();
  #pragma unroll
  for (int i = 0; i < 16; ++i) {
    const int tl2 = cb + i;
    const int cl2 = tl;
    xnT[((size_t)(b * TT + t0 + tl2)) * CC + c0 + cl2] = tile[tl2][cl2];
  }
}

// ======== GEMM core (128x128 tile, BK=32, dbuf, swizzled; see R5 notes) ========
// Epilogue (R6): each 64-aligned o-chunk is exactly one (head, Q|K|V) slab.
// Q/K: cvt_pk-packed uint2 (8B/lane) direct stores. V: LDS transpose -> full-line
// coalesced 16B stores (at most one V chunk per block; LDS is free after K-loop).

// ---------------- K2: QKV GEMM  (o,t) tiles, K=C ----------------
__global__ __launch_bounds__(256) void k_qkv_gemm(const __hip_bfloat16* __restrict__ Wq,
                                                  const __hip_bfloat16* __restrict__ Xt,
                                                  const float* __restrict__ bias,
                                                  __hip_bfloat16* __restrict__ Qb,
                                                  __hip_bfloat16* __restrict__ Kb,
                                                  __hip_bfloat16* __restrict__ Vb) {
  __shared__ __hip_bfloat16 S[2][2][128 * 32];   // [buf][A/B][tile]; 32 KB
  const int tid  = threadIdx.x;
  const int lane = tid & 63;
  const int wave = tid >> 6;
  const int wr = wave >> 1, wc = wave & 1;
  const int tn0 = blockIdx.x * 128;
  const int om0 = blockIdx.y * 128;
  const int b   = blockIdx.z;

  const char* Ab  = (const char*)(Wq + (size_t)om0 * CC);
  const char* Bbp = (const char*)(Xt + ((size_t)b * TT + tn0) * CC);

  f32x4 acc[4][4] = {};
  const int l15  = lane & 15;
  const int frc  = ((lane >> 4) << 3) * 2;        // frag col byte: 0,16,32,48
  const int rsw  = ((l15 >> 1) & 3) << 4;         // read-side XOR (row bits 1-2)

  int srow[2], scsw[2], sdst[2];
  #pragma unroll
  for (int i = 0; i < 2; ++i) {
    const int o = (i * 256 + tid) * 16;
    const int r = o >> 6, c = o & 63;
    srow[i] = r;
    scsw[i] = c ^ (((r >> 1) & 3) << 4);
    sdst[i] = (i * 256 + wave * 64) * 16;         // wave-uniform dest base (bytes)
  }

  auto stage = [&](int buf, int k0) {
    const int kb = k0 * 2;
    #pragma unroll
    for (int i = 0; i < 2; ++i) {
      load_lds16(Ab  + (size_t)srow[i] * 1024 + kb + scsw[i], (char*)S[buf][0] + sdst[i]);
      load_lds16(Bbp + (size_t)srow[i] * 1024 + kb + scsw[i], (char*)S[buf][1] + sdst[i]);
    }
  };

  stage(0, 0);
  __syncthreads();

  for (int kt = 0; kt < 16; ++kt) {
    const int buf = kt & 1;
    if (kt < 15) stage(buf ^ 1, (kt + 1) * 32);

    const char* Asb = (const char*)S[buf][0];
    const char* Bsb = (const char*)S[buf][1];
    bf16x8s af[4], bfr[4];
    #pragma unroll
    for (int mf = 0; mf < 4; ++mf)
      af[mf] = *(const bf16x8s*)(Asb + (wr * 64 + mf * 16 + l15) * 64 + (frc ^ rsw));
    #pragma unroll
    for (int nf = 0; nf < 4; ++nf)
      bfr[nf] = *(const bf16x8s*)(Bsb + (wc * 64 + nf * 16 + l15) * 64 + (frc ^ rsw));
    #pragma unroll
    for (int mf = 0; mf < 4; ++mf)
      #pragma unroll
      for (int nf = 0; nf < 4; ++nf)
        acc[mf][nf] = __builtin_amdgcn_mfma_f32_16x16x32_bf16(af[mf], bfr[nf], acc[mf][nf], 0, 0, 0);

    __syncthreads();   // drains lgkm (reads of buf done) + vmcnt (prefetch landed)
  }

  // ---------------- epilogue ----------------
  const int rg  = (lane >> 4) << 2;
  const int k0c = (om0 >> 6) % 3;                       // kind of chunk 0
  const int myKind = (wr == 0) ? k0c : (k0c + 1) % 3;   // 0=Q 1=K 2=V
  const int oc  = om0 + wr * 64;
  const int bh  = b * NH + oc / 192;
  const int vwr = (k0c == 2) ? 0 : (((k0c + 1) % 3 == 2) ? 1 : -1);
  __hip_bfloat16* Vt = &S[0][0][0];                     // 64 x 136 transpose tile

  if (myKind == 2) {
    // V: acc(+bias) -> LDS [d][136] transpose tile
    #pragma unroll
    for (int mf = 0; mf < 4; ++mf)
      #pragma unroll
      for (int j = 0; j < 4; ++j) {
        const int d = mf * 16 + rg + j;
        const float bv = bias[oc + d];
        #pragma unroll
        for (int nf = 0; nf < 4; ++nf) {
          const int tl = wc * 64 + nf * 16 + l15;
          Vt[d * 136 + tl] = __float2bfloat16(acc[mf][nf][j] + bv);
        }
      }
  } else {
    const float qs = (myKind == 0) ? 0.125f : 1.0f;     // scale^2 folded into Q
    __hip_bfloat16* outB = (myKind == 0) ? Qb : Kb;
    #pragma unroll
    for (int mf = 0; mf < 4; ++mf) {
      const float b0 = bias[oc + mf * 16 + rg + 0];
      const float b1 = bias[oc + mf * 16 + rg + 1];
      const float b2 = bias[oc + mf * 16 + rg + 2];
      const float b3 = bias[oc + mf * 16 + rg + 3];
      #pragma unroll
      for (int nf = 0; nf < 4; ++nf) {
        const int t = tn0 + wc * 64 + nf * 16 + l15;
        unsigned int lo = cvtpk_bf16((acc[mf][nf][0] + b0) * qs, (acc[mf][nf][1] + b1) * qs);
        unsigned int hi = cvtpk_bf16((acc[mf][nf][2] + b2) * qs, (acc[mf][nf][3] + b3) * qs);
        *(uint2*)&outB[((size_t)bh * TT + t) * CHD + mf * 16 + rg] = make_uint2(lo, hi);
      }
    }
  }

  if (vwr >= 0) {
    __syncthreads();
    const int bhv = b * NH + (om0 + vwr * 64) / 192;
    const int d   = tid >> 2;
    const int tc  = (tid & 3) * 32;
    const __hip_bfloat16* src = Vt + d * 136 + tc;
    __hip_bfloat16* dst = Vb + ((size_t)bhv * CHD + d) * TT + tn0 + tc;
    #pragma unroll
    for (int i = 0; i < 4; ++i)
      *(uint4*)(dst + 8 * i) = *(const uint4*)(src + 8 * i);
  }
}

// ---------------- K4: flash attention, swapped-operand 32x32, LDS-staged K/V ----------------
// (unchanged from R4/R5 — validated)
__global__ __launch_bounds__(256) void k_attn(const __hip_bfloat16* __restrict__ Qb,
                                              const __hip_bfloat16* __restrict__ Kb,
                                              const __hip_bfloat16* __restrict__ Vb,
                                              __hip_bfloat16* __restrict__ aT) {
  const int lane = threadIdx.x & 63;
  const int wave = threadIdx.x >> 6;
  const int bh   = blockIdx.y;
  const int q0   = blockIdx.x * 128 + wave * 32;   // 32 q-rows per wave
  const int l31  = lane & 31;
  const int hi8  = (lane >> 5) << 3;

  __shared__ char lds[2][16384];                   // per buf: K tile [0,8K), V tile [8K,16K)

  const __hip_bfloat16* Qh = Qb + (size_t)bh * TT * CHD;
  const __hip_bfloat16* Kh = Kb + (size_t)bh * TT * CHD;
  const __hip_bfloat16* Vh = Vb + (size_t)bh * CHD * TT;

  auto stage = [&](int buf, int kv0) {
    const char* kg = (const char*)(Kh + (size_t)kv0 * CHD);   // contiguous 8KB
    const char* vg = (const char*)Vh + (size_t)kv0 * 2;       // row stride 2048B
    #pragma unroll
    for (int i = 0; i < 2; ++i) {
      const int slot = wave * 128 + i * 64 + lane;            // 0..511
      const int o = slot * 16;
      const int r = o >> 7;
      const int cs = o & 127;
      const int swc = cs ^ ((r & 7) << 4);
      load_lds16(kg + (o & ~127) + swc, &lds[buf][(wave * 128 + i * 64) * 16]);
      load_lds16(vg + r * 2048 + swc,   &lds[buf][8192 + (wave * 128 + i * 64) * 16]);
    }
  };

  bf16x8s aq[4];
  #pragma unroll
  for (int d = 0; d < 4; ++d)
    aq[d] = *(const bf16x8s*)&Qh[(size_t)(q0 + l31) * CHD + d * 16 + hi8];

  f32x16 oacc0 = {}, oacc1 = {};
  float m_run = -1e30f, l_run = 0.f;

  const int sw = (l31 & 7) << 4;          // read-side XOR (same for rows r and r+32)
  const int cb = hi8 * 2;                 // byte offset of this half's 16B within a 32-col span

  stage(0, 0);
  __syncthreads();                        // drains vmcnt before first reads

  for (int st = 0; st < 16; ++st) {
    const int buf = st & 1;
    if (st < 15) stage(buf ^ 1, (st + 1) * 64);   // async prefetch next tile

    const char* kb = lds[buf];
    const char* vb = lds[buf] + 8192;

    bf16x8s kf0[4], kf1[4];
    #pragma unroll
    for (int d = 0; d < 4; ++d) {
      const int col = d * 32 + cb;
      kf0[d] = *(const bf16x8s*)(kb + l31 * 128        + (col ^ sw));
      kf1[d] = *(const bf16x8s*)(kb + (32 + l31) * 128 + (col ^ sw));
    }

    f32x16 s0 = {}, s1 = {};
    __builtin_amdgcn_s_setprio(1);
    #pragma unroll
    for (int d = 0; d < 4; ++d) {
      s0 = __builtin_amdgcn_mfma_f32_32x32x16_bf16(kf0[d], aq[d], s0, 0, 0, 0);
      s1 = __builtin_amdgcn_mfma_f32_32x32x16_bf16(kf1[d], aq[d], s1, 0, 0, 0);
    }
    __builtin_amdgcn_s_setprio(0);

    bf16x8s vf0[4], vf1[4];
    #pragma unroll
    for (int ks = 0; ks < 4; ++ks) {
      const int col = ks * 32 + cb;
      vf0[ks] = *(const bf16x8s*)(vb + l31 * 128        + (col ^ sw));
      vf1[ks] = *(const bf16x8s*)(vb + (32 + l31) * 128 + (col ^ sw));
    }

    float t16[16];
    #pragma unroll
    for (int i = 0; i < 16; ++i) t16[i] = fmaxf(s0[i], s1[i]);
    float t8[8];
    #pragma unroll
    for (int i = 0; i < 8; ++i) t8[i] = fmaxf(t16[i], t16[i + 8]);
    float t4[4];
    #pragma unroll
    for (int i = 0; i < 4; ++i) t4[i] = fmaxf(t8[i], t8[i + 4]);
    float lmax = fmaxf(fmaxf(t4[0], t4[1]), fmaxf(t4[2], t4[3]));
    float pmax = fmaxf(lmax, __shfl_xor(lmax, 32));

    if (!__all(pmax <= m_run + 8.0f)) {
      const float mnew  = fmaxf(m_run, pmax);
      const float alpha = __expf(m_run - mnew);
      m_run = mnew;
      l_run *= alpha;
      #pragma unroll
      for (int i = 0; i < 16; ++i) { oacc0[i] *= alpha; oacc1[i] *= alpha; }
    }

    #pragma unroll
    for (int i = 0; i < 16; ++i) s0[i] = __expf(s0[i] - m_run);
    #pragma unroll
    for (int i = 0; i < 16; ++i) s1[i] = __expf(s1[i] - m_run);
    float a8[8];
    #pragma unroll
    for (int i = 0; i < 8; ++i) a8[i] = (s0[i] + s0[i + 8]) + (s1[i] + s1[i + 8]);
    float a4[4];
    #pragma unroll
    for (int i = 0; i < 4; ++i) a4[i] = a8[i] + a8[i + 4];
    float lsum = (a4[0] + a4[1]) + (a4[2] + a4[3]);
    lsum += __shfl_xor(lsum, 32);
    l_run += lsum;

    unsigned int wa[8], wb[8];
    #pragma unroll
    for (int g = 0; g < 4; ++g) {
      wa[g]     = cvtpk_bf16(s0[4 * g + 0], s0[4 * g + 1]);
      wb[g]     = cvtpk_bf16(s0[4 * g + 2], s0[4 * g + 3]);
      wa[g + 4] = cvtpk_bf16(s1[4 * g + 0], s1[4 * g + 1]);
      wb[g + 4] = cvtpk_bf16(s1[4 * g + 2], s1[4 * g + 3]);
    }

    __builtin_amdgcn_s_setprio(1);
    #pragma unroll
    for (int ks = 0; ks < 4; ++ks) {
      unsigned int x0, y0, x1, y1;
      plswap(wa[2 * ks], wa[2 * ks + 1], x0, y0);
      plswap(wb[2 * ks], wb[2 * ks + 1], x1, y1);
      bf16x8s pf = __builtin_bit_cast(bf16x8s, (u32x4){x0, x1, y0, y1});
      oacc0 = __builtin_amdgcn_mfma_f32_32x32x16_bf16(vf0[ks], pf, oacc0, 0, 0, 0);
      oacc1 = __builtin_amdgcn_mfma_f32_32x32x16_bf16(vf1[ks], pf, oacc1, 0, 0, 0);
    }
    __builtin_amdgcn_s_setprio(0);

    __syncthreads();
  }

  const int b = bh >> 3, h = bh & 7;
  const float rl = 1.0f / l_run;
  const int t = q0 + l31;
  __hip_bfloat16* arow = aT + ((size_t)(b * TT + t)) * CC + h * CHD;
  const int hi4 = hi8 >> 1;
  #pragma unroll
  for (int rr = 0; rr < 4; ++rr) {
    {
      const int c0 = rr * 8 + hi4;
      unsigned int lo = cvtpk_bf16(oacc0[4 * rr + 0] * rl, oacc0[4 * rr + 1] * rl);
      unsigned int hw = cvtpk_bf16(oacc0[4 * rr + 2] * rl, oacc0[4 * rr + 3] * rl);
      *(uint2*)&arow[c0] = make_uint2(lo, hw);
    }
    {
      const int c0 = 32 + rr * 8 + hi4;
      unsigned int lo = cvtpk_bf16(oacc1[4 * rr + 0] * rl, oacc1[4 * rr + 1] * rl);
      unsigned int hw = cvtpk_bf16(oacc1[4 * rr + 2] * rl, oacc1[4 * rr + 3] * rl);
      *(uint2*)&arow[c0] = make_uint2(lo, hw);
    }
  }
}

// ---------------- K5: proj GEMM + bias + xn residual ----------------
__global__ __launch_bounds__(256) void k_proj_gemm(const __hip_bfloat16* __restrict__ Wp,
                                                   const __hip_bfloat16* __restrict__ At,
                                                   const float* __restrict__ bias,
                                                   const float* __restrict__ x,
                                                   const float* __restrict__ mean,
                                                   const float* __restrict__ rstd,
                                                   float* __restrict__ out) {
  __shared__ __hip_bfloat16 As2[2][128 * 32];
  __shared__ __hip_bfloat16 Bs2[2][128 * 32];
  const int tid  = threadIdx.x;
  const int lane = tid & 63;
  const int wave = tid >> 6;
  const int wr = wave >> 1, wc = wave & 1;
  const int tn0 = blockIdx.x * 128;
  const int om0 = blockIdx.y * 128;
  const int b   = blockIdx.z;

  const char* Ab  = (const char*)(Wp + (size_t)om0 * CC);
  const char* Bbp = (const char*)(At + ((size_t)b * TT + tn0) * CC);

  f32x4 acc[4][4] = {};
  const int l15  = lane & 15;
  const int frc  = ((lane >> 4) << 3) * 2;
  const int rsw  = ((l15 >> 1) & 3) << 4;

  int srow[2], scsw[2], sdst[2];
  #pragma unroll
  for (int i = 0; i < 2; ++i) {
    const int o = (i * 256 + tid) * 16;
    const int r = o >> 6, c = o & 63;
    srow[i] = r;
    scsw[i] = c ^ (((r >> 1) & 3) << 4);
    sdst[i] = (i * 256 + wave * 64) * 16;
  }

  auto stage = [&](int buf, int k0) {
    const int kb = k0 * 2;
    #pragma unroll
    for (int i = 0; i < 2; ++i) {
      load_lds16(Ab  + (size_t)srow[i] * 1024 + kb + scsw[i], (char*)As2[buf] + sdst[i]);
      load_lds16(Bbp + (size_t)srow[i] * 1024 + kb + scsw[i], (char*)Bs2[buf] + sdst[i]);
    }
  };

  stage(0, 0);
  __syncthreads();

  for (int kt = 0; kt < 16; ++kt) {
    const int buf = kt & 1;
    if (kt < 15) stage(buf ^ 1, (kt + 1) * 32);

    const char* Asb = (const char*)As2[buf];
    const char* Bsb = (const char*)Bs2[buf];
    bf16x8s af[4], bfr[4];
    #pragma unroll
    for (int mf = 0; mf < 4; ++mf)
      af[mf] = *(const bf16x8s*)(Asb + (wr * 64 + mf * 16 + l15) * 64 + (frc ^ rsw));
    #pragma unroll
    for (int nf = 0; nf < 4; ++nf)
      bfr[nf] = *(const bf16x8s*)(Bsb + (wc * 64 + nf * 16 + l15) * 64 + (frc ^ rsw));
    #pragma unroll
    for (int mf = 0; mf < 4; ++mf)
      #pragma unroll
      for (int nf = 0; nf < 4; ++nf)
        acc[mf][nf] = __builtin_amdgcn_mfma_f32_16x16x32_bf16(af[mf], bfr[nf], acc[mf][nf], 0, 0, 0);

    __syncthreads();
  }

  const int rg = (lane >> 4) << 2;
  #pragma unroll
  for (int mf = 0; mf < 4; ++mf) {
    #pragma unroll
    for (int j = 0; j < 4; ++j) {
      const int o = om0 + wr * 64 + mf * 16 + rg + j;
      const int gco = b * CC + o;
      const float bv = bias[o];
      const float mu = mean[gco], rs = rstd[gco];
      #pragma unroll
      for (int nf = 0; nf < 4; ++nf) {
        const int t = tn0 + wc * 64 + nf * 16 + l15;
        const size_t xi = (size_t)gco * TT + t;
        float xn = (x[xi] - mu) * rs;
        out[xi] = xn + acc[mf][nf][j] + bv;
      }
    }
  }
}

extern "C" void kernel_launch(void* const* d_in, const int* in_sizes, int n_in,
                              void* d_out, int out_size, void* d_ws, size_t ws_size,
                              hipStream_t stream) {
  const float* x  = (const float*)d_in[0];
  const float* wq = (const float*)d_in[1];
  const float* bq = (const float*)d_in[2];
  const float* wp = (const float*)d_in[3];
  const float* bp = (const float*)d_in[4];
  float* out = (float*)d_out;

  char* ws = (char*)d_ws;
  __hip_bfloat16* wqb = (__hip_bfloat16*)(ws);                  // 1536*512*2      = 1,572,864
  __hip_bfloat16* wpb = (__hip_bfloat16*)(ws + 1572864);        // 512*512*2       =   524,288
  float*          mean = (float*)(ws + 2097152);                // 8192*4
  float*          rstd = (float*)(ws + 2129920);                // 8192*4
  __hip_bfloat16* xnT = (__hip_bfloat16*)(ws + 2162688);        // 16*1024*512*2   = 16,777,216
  __hip_bfloat16* Qb  = (__hip_bfloat16*)(ws + 18939904);       // 128*1024*64*2
  __hip_bfloat16* Kb  = (__hip_bfloat16*)(ws + 35717120);
  __hip_bfloat16* Vb  = (__hip_bfloat16*)(ws + 52494336);       // ends 69,271,552
  __hip_bfloat16* aT  = xnT;   // alias: xnT fully consumed by k_qkv_gemm before k_attn writes aT

  k_convert_w<<<4096, 256, 0, stream>>>(wq, wp, wqb, wpb);
  k_ln_stats<<<BB * CC, 256, 0, stream>>>(x, mean, rstd);
  k_normT<<<dim3(TT / 64, CC / 64, BB), 256, 0, stream>>>(x, mean, rstd, xnT);
  k_qkv_gemm<<<dim3(TT / 128, OQ / 128, BB), 256, 0, stream>>>(wqb, xnT, bq, Qb, Kb, Vb);
  k_attn<<<dim3(TT / 128, BB * NH), 256, 0, stream>>>(Qb, Kb, Vb, aT);
  k_proj_gemm<<<dim3(TT / 128, CC / 128, BB), 256, 0, stream>>>(wpb, aT, bp, x, mean, rstd, out);
}

// Round 7
// 220.317 us; speedup vs baseline: 1.9083x; 1.0179x over previous
//
#include <hip/hip_runtime.h>
#include <hip/hip_bf16.h>

using bf16x8s = __attribute__((ext_vector_type(8))) short;
using f32x4   = __attribute__((ext_vector_type(4))) float;
using f32x16  = __attribute__((ext_vector_type(16))) float;
using u32x4   = __attribute__((ext_vector_type(4))) unsigned int;

#define DEVI __device__ __forceinline__

static constexpr int BB  = 16;    // batch
static constexpr int CC  = 512;   // channels
static constexpr int TT  = 1024;  // tokens = 32*32
static constexpr int OQ  = 1536;  // 3*C
static constexpr int NH  = 8;     // heads
static constexpr int CHD = 64;    // head dim

DEVI void load_lds16(const void* g, void* l) {
  __builtin_amdgcn_global_load_lds((const __attribute__((address_space(1))) void*)g,
                                   (__attribute__((address_space(3))) void*)l,
                                   16, 0, 0);
}

DEVI unsigned int cvtpk_bf16(float lo, float hi) {
  unsigned int r;
  asm("v_cvt_pk_bf16_f32 %0, %1, %2" : "=v"(r) : "v"(lo), "v"(hi));
  return r;
}

DEVI float fexp2(float x) {            // v_exp_f32 = 2^x (scores are log2-domain)
  float r;
  asm("v_exp_f32 %0, %1" : "=v"(r) : "v"(x));
  return r;
}

// permlane32_swap(a,b): x = (lane>=32 ? b-of-partner : own a); y = (lane>=32 ? own b : a-of-partner)
DEVI void plswap(unsigned int a, unsigned int b, unsigned int& x, unsigned int& y) {
#if __has_builtin(__builtin_amdgcn_permlane32_swap)
  auto r = __builtin_amdgcn_permlane32_swap((int)a, (int)b, false, false);
  x = (unsigned int)r[0];
  y = (unsigned int)r[1];
#else
  unsigned int pa = (unsigned int)__shfl_xor((int)a, 32);
  unsigned int pb = (unsigned int)__shfl_xor((int)b, 32);
  const bool hi = (threadIdx.x & 32) != 0;
  x = hi ? pb : a;
  y = hi ? b : pa;
#endif
}

// ---------------- K0: convert weights fp32 -> bf16 ----------------
__global__ __launch_bounds__(256) void k_convert_w(const float* __restrict__ wq,
                                                   const float* __restrict__ wp,
                                                   __hip_bfloat16* __restrict__ wqb,
                                                   __hip_bfloat16* __restrict__ wpb) {
  int i = blockIdx.x * 256 + threadIdx.x;
  const int NQ = OQ * CC;                 // 786432
  if (i < NQ) wqb[i] = __float2bfloat16(wq[i]);
  else        wpb[i - NQ] = __float2bfloat16(wp[i - NQ]);   // grid covers NQ + 512*512 exactly
}

// ---------------- K1a: LayerNorm stats per (b,c) over T ----------------
__global__ __launch_bounds__(256) void k_ln_stats(const float* __restrict__ x,
                                                  float* __restrict__ mean,
                                                  float* __restrict__ rstd) {
  const int row = blockIdx.x;                    // b*C + c
  const float4* xv = (const float4*)(x + (size_t)row * TT);
  float4 v = xv[threadIdx.x];
  float s = v.x + v.y + v.z + v.w;
  float q = v.x * v.x + v.y * v.y + v.z * v.z + v.w * v.w;
  #pragma unroll
  for (int off = 1; off < 64; off <<= 1) {
    s += __shfl_xor(s, off);
    q += __shfl_xor(q, off);
  }
  __shared__ float ss[4], sq[4];
  const int wave = threadIdx.x >> 6;
  if ((threadIdx.x & 63) == 0) { ss[wave] = s; sq[wave] = q; }
  __syncthreads();
  if (threadIdx.x == 0) {
    float S = ss[0] + ss[1] + ss[2] + ss[3];
    float Q = sq[0] + sq[1] + sq[2] + sq[3];
    float m = S * (1.0f / TT);
    float var = Q * (1.0f / TT) - m * m;
    mean[row] = m;
    rstd[row] = 1.0f / sqrtf(var + 1e-5f);
  }
}

// ---------------- K1b: normalize + transpose -> xnT[b][t][c] bf16 ----------------
__global__ __launch_bounds__(256) void k_normT(const float* __restrict__ x,
                                               const float* __restrict__ mean,
                                               const float* __restrict__ rstd,
                                               __hip_bfloat16* __restrict__ xnT) {
  const int t0 = blockIdx.x * 64;
  const int c0 = blockIdx.y * 64;
  const int b  = blockIdx.z;
  __shared__ __hip_bfloat16 tile[64][66];        // stride 66 elems = 132B: conflict-free
  const int tl = threadIdx.x & 63;
  const int cb = (threadIdx.x >> 6) * 16;
  #pragma unroll
  for (int i = 0; i < 16; ++i) {
    const int cl = cb + i;
    const int gc = b * CC + c0 + cl;
    float v = x[(size_t)gc * TT + t0 + tl];
    float xn = (v - mean[gc]) * rstd[gc];
    tile[tl][cl] = __float2bfloat16(xn);
  }
  __syncthreads();
  #pragma unroll
  for (int i = 0; i < 16; ++i) {
    const int tl2 = cb + i;
    const int cl2 = tl;
    xnT[((size_t)(b * TT + t0 + tl2)) * CC + c0 + cl2] = tile[tl2][cl2];
  }
}

// ======== GEMM core (128x128 tile, BK=32, dbuf, swizzled; see R5 notes) ========
// Epilogue (R6): Q/K cvt_pk uint2 stores; V via LDS transpose, full-line stores.
// R7: Q scale now 0.125*log2e (softmax runs in log2 domain, v_exp_f32-native).

// ---------------- K2: QKV GEMM  (o,t) tiles, K=C ----------------
__global__ __launch_bounds__(256) void k_qkv_gemm(const __hip_bfloat16* __restrict__ Wq,
                                                  const __hip_bfloat16* __restrict__ Xt,
                                                  const float* __restrict__ bias,
                                                  __hip_bfloat16* __restrict__ Qb,
                                                  __hip_bfloat16* __restrict__ Kb,
                                                  __hip_bfloat16* __restrict__ Vb) {
  __shared__ __hip_bfloat16 S[2][2][128 * 32];   // [buf][A/B][tile]; 32 KB
  const int tid  = threadIdx.x;
  const int lane = tid & 63;
  const int wave = tid >> 6;
  const int wr = wave >> 1, wc = wave & 1;
  const int tn0 = blockIdx.x * 128;
  const int om0 = blockIdx.y * 128;
  const int b   = blockIdx.z;

  const char* Ab  = (const char*)(Wq + (size_t)om0 * CC);
  const char* Bbp = (const char*)(Xt + ((size_t)b * TT + tn0) * CC);

  f32x4 acc[4][4] = {};
  const int l15  = lane & 15;
  const int frc  = ((lane >> 4) << 3) * 2;        // frag col byte: 0,16,32,48
  const int rsw  = ((l15 >> 1) & 3) << 4;         // read-side XOR (row bits 1-2)

  int srow[2], scsw[2], sdst[2];
  #pragma unroll
  for (int i = 0; i < 2; ++i) {
    const int o = (i * 256 + tid) * 16;
    const int r = o >> 6, c = o & 63;
    srow[i] = r;
    scsw[i] = c ^ (((r >> 1) & 3) << 4);
    sdst[i] = (i * 256 + wave * 64) * 16;         // wave-uniform dest base (bytes)
  }

  auto stage = [&](int buf, int k0) {
    const int kb = k0 * 2;
    #pragma unroll
    for (int i = 0; i < 2; ++i) {
      load_lds16(Ab  + (size_t)srow[i] * 1024 + kb + scsw[i], (char*)S[buf][0] + sdst[i]);
      load_lds16(Bbp + (size_t)srow[i] * 1024 + kb + scsw[i], (char*)S[buf][1] + sdst[i]);
    }
  };

  stage(0, 0);
  __syncthreads();

  for (int kt = 0; kt < 16; ++kt) {
    const int buf = kt & 1;
    if (kt < 15) stage(buf ^ 1, (kt + 1) * 32);

    const char* Asb = (const char*)S[buf][0];
    const char* Bsb = (const char*)S[buf][1];
    bf16x8s af[4], bfr[4];
    #pragma unroll
    for (int mf = 0; mf < 4; ++mf)
      af[mf] = *(const bf16x8s*)(Asb + (wr * 64 + mf * 16 + l15) * 64 + (frc ^ rsw));
    #pragma unroll
    for (int nf = 0; nf < 4; ++nf)
      bfr[nf] = *(const bf16x8s*)(Bsb + (wc * 64 + nf * 16 + l15) * 64 + (frc ^ rsw));
    #pragma unroll
    for (int mf = 0; mf < 4; ++mf)
      #pragma unroll
      for (int nf = 0; nf < 4; ++nf)
        acc[mf][nf] = __builtin_amdgcn_mfma_f32_16x16x32_bf16(af[mf], bfr[nf], acc[mf][nf], 0, 0, 0);

    __syncthreads();   // drains lgkm (reads of buf done) + vmcnt (prefetch landed)
  }

  // ---------------- epilogue ----------------
  const int rg  = (lane >> 4) << 2;
  const int k0c = (om0 >> 6) % 3;                       // kind of chunk 0
  const int myKind = (wr == 0) ? k0c : (k0c + 1) % 3;   // 0=Q 1=K 2=V
  const int oc  = om0 + wr * 64;
  const int bh  = b * NH + oc / 192;
  const int vwr = (k0c == 2) ? 0 : (((k0c + 1) % 3 == 2) ? 1 : -1);
  __hip_bfloat16* Vt = &S[0][0][0];                     // 64 x 136 transpose tile

  if (myKind == 2) {
    #pragma unroll
    for (int mf = 0; mf < 4; ++mf)
      #pragma unroll
      for (int j = 0; j < 4; ++j) {
        const int d = mf * 16 + rg + j;
        const float bv = bias[oc + d];
        #pragma unroll
        for (int nf = 0; nf < 4; ++nf) {
          const int tl = wc * 64 + nf * 16 + l15;
          Vt[d * 136 + tl] = __float2bfloat16(acc[mf][nf][j] + bv);
        }
      }
  } else {
    // Q scale: softmax scale^2 (0.125) * log2e -> scores arrive in log2 domain
    const float qs = (myKind == 0) ? 0.18033688f : 1.0f;
    __hip_bfloat16* outB = (myKind == 0) ? Qb : Kb;
    #pragma unroll
    for (int mf = 0; mf < 4; ++mf) {
      const float b0 = bias[oc + mf * 16 + rg + 0];
      const float b1 = bias[oc + mf * 16 + rg + 1];
      const float b2 = bias[oc + mf * 16 + rg + 2];
      const float b3 = bias[oc + mf * 16 + rg + 3];
      #pragma unroll
      for (int nf = 0; nf < 4; ++nf) {
        const int t = tn0 + wc * 64 + nf * 16 + l15;
        unsigned int lo = cvtpk_bf16((acc[mf][nf][0] + b0) * qs, (acc[mf][nf][1] + b1) * qs);
        unsigned int hi = cvtpk_bf16((acc[mf][nf][2] + b2) * qs, (acc[mf][nf][3] + b3) * qs);
        *(uint2*)&outB[((size_t)bh * TT + t) * CHD + mf * 16 + rg] = make_uint2(lo, hi);
      }
    }
  }

  if (vwr >= 0) {
    __syncthreads();
    const int bhv = b * NH + (om0 + vwr * 64) / 192;
    const int d   = tid >> 2;
    const int tc  = (tid & 3) * 32;
    const __hip_bfloat16* src = Vt + d * 136 + tc;
    __hip_bfloat16* dst = Vb + ((size_t)bhv * CHD + d) * TT + tn0 + tc;
    #pragma unroll
    for (int i = 0; i < 4; ++i)
      *(uint4*)(dst + 8 * i) = *(const uint4*)(src + 8 * i);
  }
}

// ---------------- K4: flash attention, swapped-operand 32x32, LDS-staged K/V ----------------
// R7: 1D grid, bid = qt*128 + bh  ->  all 8 q-tile blocks of a bh are == mod 8
// (same XCD, shared L2 copy of K/V). Softmax in log2 domain (raw v_exp_f32).
__global__ __launch_bounds__(256) void k_attn(const __hip_bfloat16* __restrict__ Qb,
                                              const __hip_bfloat16* __restrict__ Kb,
                                              const __hip_bfloat16* __restrict__ Vb,
                                              __hip_bfloat16* __restrict__ aT) {
  const int lane = threadIdx.x & 63;
  const int wave = threadIdx.x >> 6;
  const int bh   = blockIdx.x & 127;
  const int qt   = blockIdx.x >> 7;
  const int q0   = qt * 128 + wave * 32;           // 32 q-rows per wave
  const int l31  = lane & 31;
  const int hi8  = (lane >> 5) << 3;

  __shared__ char lds[2][16384];                   // per buf: K tile [0,8K), V tile [8K,16K)

  const __hip_bfloat16* Qh = Qb + (size_t)bh * TT * CHD;
  const __hip_bfloat16* Kh = Kb + (size_t)bh * TT * CHD;
  const __hip_bfloat16* Vh = Vb + (size_t)bh * CHD * TT;

  auto stage = [&](int buf, int kv0) {
    const char* kg = (const char*)(Kh + (size_t)kv0 * CHD);   // contiguous 8KB
    const char* vg = (const char*)Vh + (size_t)kv0 * 2;       // row stride 2048B
    #pragma unroll
    for (int i = 0; i < 2; ++i) {
      const int slot = wave * 128 + i * 64 + lane;            // 0..511
      const int o = slot * 16;
      const int r = o >> 7;
      const int cs = o & 127;
      const int swc = cs ^ ((r & 7) << 4);
      load_lds16(kg + (o & ~127) + swc, &lds[buf][(wave * 128 + i * 64) * 16]);
      load_lds16(vg + r * 2048 + swc,   &lds[buf][8192 + (wave * 128 + i * 64) * 16]);
    }
  };

  bf16x8s aq[4];
  #pragma unroll
  for (int d = 0; d < 4; ++d)
    aq[d] = *(const bf16x8s*)&Qh[(size_t)(q0 + l31) * CHD + d * 16 + hi8];

  f32x16 oacc0 = {}, oacc1 = {};
  float m_run = -1e30f, l_run = 0.f;

  const int sw = (l31 & 7) << 4;          // read-side XOR (same for rows r and r+32)
  const int cb = hi8 * 2;                 // byte offset of this half's 16B within a 32-col span

  stage(0, 0);
  __syncthreads();                        // drains vmcnt before first reads

  for (int st = 0; st < 16; ++st) {
    const int buf = st & 1;
    if (st < 15) stage(buf ^ 1, (st + 1) * 64);   // async prefetch next tile

    const char* kb = lds[buf];
    const char* vb = lds[buf] + 8192;

    bf16x8s kf0[4], kf1[4];
    #pragma unroll
    for (int d = 0; d < 4; ++d) {
      const int col = d * 32 + cb;
      kf0[d] = *(const bf16x8s*)(kb + l31 * 128        + (col ^ sw));
      kf1[d] = *(const bf16x8s*)(kb + (32 + l31) * 128 + (col ^ sw));
    }

    f32x16 s0 = {}, s1 = {};
    __builtin_amdgcn_s_setprio(1);
    #pragma unroll
    for (int d = 0; d < 4; ++d) {
      s0 = __builtin_amdgcn_mfma_f32_32x32x16_bf16(kf0[d], aq[d], s0, 0, 0, 0);
      s1 = __builtin_amdgcn_mfma_f32_32x32x16_bf16(kf1[d], aq[d], s1, 0, 0, 0);
    }
    __builtin_amdgcn_s_setprio(0);

    bf16x8s vf0[4], vf1[4];
    #pragma unroll
    for (int ks = 0; ks < 4; ++ks) {
      const int col = ks * 32 + cb;
      vf0[ks] = *(const bf16x8s*)(vb + l31 * 128        + (col ^ sw));
      vf1[ks] = *(const bf16x8s*)(vb + (32 + l31) * 128 + (col ^ sw));
    }

    float t16[16];
    #pragma unroll
    for (int i = 0; i < 16; ++i) t16[i] = fmaxf(s0[i], s1[i]);
    float t8[8];
    #pragma unroll
    for (int i = 0; i < 8; ++i) t8[i] = fmaxf(t16[i], t16[i + 8]);
    float t4[4];
    #pragma unroll
    for (int i = 0; i < 4; ++i) t4[i] = fmaxf(t8[i], t8[i + 4]);
    float lmax = fmaxf(fmaxf(t4[0], t4[1]), fmaxf(t4[2], t4[3]));
    float pmax = fmaxf(lmax, __shfl_xor(lmax, 32));

    // defer-max: log2 domain, THR = 8*log2e ~= 11.5
    if (!__all(pmax <= m_run + 11.5f)) {
      const float mnew  = fmaxf(m_run, pmax);
      const float alpha = fexp2(m_run - mnew);
      m_run = mnew;
      l_run *= alpha;
      #pragma unroll
      for (int i = 0; i < 16; ++i) { oacc0[i] *= alpha; oacc1[i] *= alpha; }
    }

    #pragma unroll
    for (int i = 0; i < 16; ++i) s0[i] = fexp2(s0[i] - m_run);
    #pragma unroll
    for (int i = 0; i < 16; ++i) s1[i] = fexp2(s1[i] - m_run);
    float a8[8];
    #pragma unroll
    for (int i = 0; i < 8; ++i) a8[i] = (s0[i] + s0[i + 8]) + (s1[i] + s1[i + 8]);
    float a4[4];
    #pragma unroll
    for (int i = 0; i < 4; ++i) a4[i] = a8[i] + a8[i + 4];
    float lsum = (a4[0] + a4[1]) + (a4[2] + a4[3]);
    lsum += __shfl_xor(lsum, 32);
    l_run += lsum;

    unsigned int wa[8], wb[8];
    #pragma unroll
    for (int g = 0; g < 4; ++g) {
      wa[g]     = cvtpk_bf16(s0[4 * g + 0], s0[4 * g + 1]);
      wb[g]     = cvtpk_bf16(s0[4 * g + 2], s0[4 * g + 3]);
      wa[g + 4] = cvtpk_bf16(s1[4 * g + 0], s1[4 * g + 1]);
      wb[g + 4] = cvtpk_bf16(s1[4 * g + 2], s1[4 * g + 3]);
    }

    __builtin_amdgcn_s_setprio(1);
    #pragma unroll
    for (int ks = 0; ks < 4; ++ks) {
      unsigned int x0, y0, x1, y1;
      plswap(wa[2 * ks], wa[2 * ks + 1], x0, y0);
      plswap(wb[2 * ks], wb[2 * ks + 1], x1, y1);
      bf16x8s pf = __builtin_bit_cast(bf16x8s, (u32x4){x0, x1, y0, y1});
      oacc0 = __builtin_amdgcn_mfma_f32_32x32x16_bf16(vf0[ks], pf, oacc0, 0, 0, 0);
      oacc1 = __builtin_amdgcn_mfma_f32_32x32x16_bf16(vf1[ks], pf, oacc1, 0, 0, 0);
    }
    __builtin_amdgcn_s_setprio(0);

    __syncthreads();
  }

  const int b = bh >> 3, h = bh & 7;
  const float rl = 1.0f / l_run;
  const int t = q0 + l31;
  __hip_bfloat16* arow = aT + ((size_t)(b * TT + t)) * CC + h * CHD;
  const int hi4 = hi8 >> 1;
  #pragma unroll
  for (int rr = 0; rr < 4; ++rr) {
    {
      const int c0 = rr * 8 + hi4;
      unsigned int lo = cvtpk_bf16(oacc0[4 * rr + 0] * rl, oacc0[4 * rr + 1] * rl);
      unsigned int hw = cvtpk_bf16(oacc0[4 * rr + 2] * rl, oacc0[4 * rr + 3] * rl);
      *(uint2*)&arow[c0] = make_uint2(lo, hw);
    }
    {
      const int c0 = 32 + rr * 8 + hi4;
      unsigned int lo = cvtpk_bf16(oacc1[4 * rr + 0] * rl, oacc1[4 * rr + 1] * rl);
      unsigned int hw = cvtpk_bf16(oacc1[4 * rr + 2] * rl, oacc1[4 * rr + 3] * rl);
      *(uint2*)&arow[c0] = make_uint2(lo, hw);
    }
  }
}

// ---------------- K5: proj GEMM + bias + xn residual ----------------
__global__ __launch_bounds__(256) void k_proj_gemm(const __hip_bfloat16* __restrict__ Wp,
                                                   const __hip_bfloat16* __restrict__ At,
                                                   const float* __restrict__ bias,
                                                   const float* __restrict__ x,
                                                   const float* __restrict__ mean,
                                                   const float* __restrict__ rstd,
                                                   float* __restrict__ out) {
  __shared__ __hip_bfloat16 As2[2][128 * 32];
  __shared__ __hip_bfloat16 Bs2[2][128 * 32];
  const int tid  = threadIdx.x;
  const int lane = tid & 63;
  const int wave = tid >> 6;
  const int wr = wave >> 1, wc = wave & 1;
  const int tn0 = blockIdx.x * 128;
  const int om0 = blockIdx.y * 128;
  const int b   = blockIdx.z;

  const char* Ab  = (const char*)(Wp + (size_t)om0 * CC);
  const char* Bbp = (const char*)(At + ((size_t)b * TT + tn0) * CC);

  f32x4 acc[4][4] = {};
  const int l15  = lane & 15;
  const int frc  = ((lane >> 4) << 3) * 2;
  const int rsw  = ((l15 >> 1) & 3) << 4;

  int srow[2], scsw[2], sdst[2];
  #pragma unroll
  for (int i = 0; i < 2; ++i) {
    const int o = (i * 256 + tid) * 16;
    const int r = o >> 6, c = o & 63;
    srow[i] = r;
    scsw[i] = c ^ (((r >> 1) & 3) << 4);
    sdst[i] = (i * 256 + wave * 64) * 16;
  }

  auto stage = [&](int buf, int k0) {
    const int kb = k0 * 2;
    #pragma unroll
    for (int i = 0; i < 2; ++i) {
      load_lds16(Ab  + (size_t)srow[i] * 1024 + kb + scsw[i], (char*)As2[buf] + sdst[i]);
      load_lds16(Bbp + (size_t)srow[i] * 1024 + kb + scsw[i], (char*)Bs2[buf] + sdst[i]);
    }
  };

  stage(0, 0);
  __syncthreads();

  for (int kt = 0; kt < 16; ++kt) {
    const int buf = kt & 1;
    if (kt < 15) stage(buf ^ 1, (kt + 1) * 32);

    const char* Asb = (const char*)As2[buf];
    const char* Bsb = (const char*)Bs2[buf];
    bf16x8s af[4], bfr[4];
    #pragma unroll
    for (int mf = 0; mf < 4; ++mf)
      af[mf] = *(const bf16x8s*)(Asb + (wr * 64 + mf * 16 + l15) * 64 + (frc ^ rsw));
    #pragma unroll
    for (int nf = 0; nf < 4; ++nf)
      bfr[nf] = *(const bf16x8s*)(Bsb + (wc * 64 + nf * 16 + l15) * 64 + (frc ^ rsw));
    #pragma unroll
    for (int mf = 0; mf < 4; ++mf)
      #pragma unroll
      for (int nf = 0; nf < 4; ++nf)
        acc[mf][nf] = __builtin_amdgcn_mfma_f32_16x16x32_bf16(af[mf], bfr[nf], acc[mf][nf], 0, 0, 0);

    __syncthreads();
  }

  const int rg = (lane >> 4) << 2;
  #pragma unroll
  for (int mf = 0; mf < 4; ++mf) {
    #pragma unroll
    for (int j = 0; j < 4; ++j) {
      const int o = om0 + wr * 64 + mf * 16 + rg + j;
      const int gco = b * CC + o;
      const float bv = bias[o];
      const float mu = mean[gco], rs = rstd[gco];
      #pragma unroll
      for (int nf = 0; nf < 4; ++nf) {
        const int t = tn0 + wc * 64 + nf * 16 + l15;
        const size_t xi = (size_t)gco * TT + t;
        float xn = (x[xi] - mu) * rs;
        out[xi] = xn + acc[mf][nf][j] + bv;
      }
    }
  }
}

extern "C" void kernel_launch(void* const* d_in, const int* in_sizes, int n_in,
                              void* d_out, int out_size, void* d_ws, size_t ws_size,
                              hipStream_t stream) {
  const float* x  = (const float*)d_in[0];
  const float* wq = (const float*)d_in[1];
  const float* bq = (const float*)d_in[2];
  const float* wp = (const float*)d_in[3];
  const float* bp = (const float*)d_in[4];
  float* out = (float*)d_out;

  char* ws = (char*)d_ws;
  __hip_bfloat16* wqb = (__hip_bfloat16*)(ws);                  // 1536*512*2      = 1,572,864
  __hip_bfloat16* wpb = (__hip_bfloat16*)(ws + 1572864);        // 512*512*2       =   524,288
  float*          mean = (float*)(ws + 2097152);                // 8192*4
  float*          rstd = (float*)(ws + 2129920);                // 8192*4
  __hip_bfloat16* xnT = (__hip_bfloat16*)(ws + 2162688);        // 16*1024*512*2   = 16,777,216
  __hip_bfloat16* Qb  = (__hip_bfloat16*)(ws + 18939904);       // 128*1024*64*2
  __hip_bfloat16* Kb  = (__hip_bfloat16*)(ws + 35717120);
  __hip_bfloat16* Vb  = (__hip_bfloat16*)(ws + 52494336);       // ends 69,271,552
  __hip_bfloat16* aT  = xnT;   // alias: xnT fully consumed by k_qkv_gemm before k_attn writes aT

  k_convert_w<<<4096, 256, 0, stream>>>(wq, wp, wqb, wpb);
  k_ln_stats<<<BB * CC, 256, 0, stream>>>(x, mean, rstd);
  k_normT<<<dim3(TT / 64, CC / 64, BB), 256, 0, stream>>>(x, mean, rstd, xnT);
  k_qkv_gemm<<<dim3(TT / 128, OQ / 128, BB), 256, 0, stream>>>(wqb, xnT, bq, Qb, Kb, Vb);
  k_attn<<<1024, 256, 0, stream>>>(Qb, Kb, Vb, aT);   // 1D: bid = qt*128 + bh (XCD-local K/V)
  k_proj_gemm<<<dim3(TT / 128, CC / 128, BB), 256, 0, stream>>>(wpb, aT, bp, x, mean, rstd, out);
}